// Round 10
// baseline (445.762 us; speedup 1.0000x reference)
//
#include <hip/hip_runtime.h>

#define N_NODES 200000
#define N_EDGES 6400000
#define N_GRAPHS 512
#define RLEN 20
#define EMBED 8
#define EPS 1e-5f

#define NPB 1024                           // nodes per bucket
#define NBKT ((N_NODES + NPB - 1) / NPB)   // 196
#define CHUNK 4096                         // edges per k_bscatter block
#define CAP 36864                          // padded bucket capacity (mean 32653 + 23 sigma)

typedef unsigned short ushort_t;
typedef __attribute__((ext_vector_type(8))) short short8;
typedef __attribute__((ext_vector_type(4))) float f32x4;

__device__ inline ushort_t f32_to_bf16(float f) {
  unsigned u = __float_as_uint(f);
  unsigned r = (u + 0x7fff + ((u >> 16) & 1)) >> 16;  // RNE
  return (ushort_t)r;
}
__device__ inline float bf16_to_f32(ushort_t us) {
  return __uint_as_float(((unsigned)us) << 16);
}
__device__ inline float bfu_lo(unsigned u) { return __uint_as_float(u << 16); }
__device__ inline float bfu_hi(unsigned u) { return __uint_as_float(u & 0xFFFF0000u); }

// ---------------- bucketed CSR build (padded buckets; direct-write scatter) ----------------

__global__ void k_binit(int* __restrict__ bcursor) {
  int b = threadIdx.x;
  if (b < NBKT) bcursor[b] = b * CAP;
}

__global__ void __launch_bounds__(256) k_bscatter(const int* __restrict__ src,
                                                  const int* __restrict__ dst,
                                                  int* __restrict__ bcursor,
                                                  int* __restrict__ ebuf) {
  __shared__ int hist[256];
  __shared__ int gbase[256];
  int t = threadIdx.x;
  hist[t] = 0;
  __syncthreads();

  const int4* src4 = (const int4*)(src + blockIdx.x * CHUNK);
  const int4* dst4 = (const int4*)(dst + blockIdx.x * CHUNK);
  int e0 = blockIdx.x * CHUNK;
  int nrem = N_EDGES - e0;
  int nv = (nrem >= CHUNK ? CHUNK : nrem) >> 2;     // int4 groups (N_EDGES%4==0)

  int pk[16], bk[16], rk[16];
  #pragma unroll
  for (int g = 0; g < 4; ++g) {
    int vi = g * 256 + t;
    if (vi < nv) {
      int4 s4 = src4[vi];
      int4 d4 = dst4[vi];
      #pragma unroll
      for (int c = 0; c < 4; ++c) {
        int s = (&s4.x)[c], d = (&d4.x)[c];
        int b = d >> 10;
        pk[g * 4 + c] = s | ((d & (NPB - 1)) << 18);
        bk[g * 4 + c] = b;
        rk[g * 4 + c] = atomicAdd(&hist[b], 1);
      }
    } else {
      #pragma unroll
      for (int c = 0; c < 4; ++c) bk[g * 4 + c] = -1;
    }
  }
  __syncthreads();
  if (t < NBKT && hist[t] > 0) gbase[t] = atomicAdd(&bcursor[t], hist[t]);
  __syncthreads();
  #pragma unroll
  for (int k = 0; k < 16; ++k) {
    if (bk[k] >= 0) ebuf[gbase[bk[k]] + rk[k]] = pk[k];
  }
}

// per bucket: degrees -> rowstart/rowlen/dinv/xs, then local scatter of cols
__global__ void __launch_bounds__(256) k_bfill(const int* __restrict__ bcursor,
                                               const int* __restrict__ ebuf,
                                               const float* __restrict__ x,
                                               int* __restrict__ rowstart,
                                               int* __restrict__ rowlen,
                                               float* __restrict__ dinv,
                                               float4* __restrict__ xs,
                                               int* __restrict__ cols) {
  __shared__ int deg[NPB];
  __shared__ int cur[NPB];
  __shared__ int wsum[4];
  int b = blockIdx.x;
  int t = threadIdx.x;
  int lane = t & 63, wid = t >> 6;
  int estart = b * CAP;
  int eend = bcursor[b];           // estart + count
  int cnt = eend - estart;
  int nv = cnt >> 2;
  const int4* eb4 = (const int4*)(ebuf + estart);   // estart*4 % 16 == 0
  for (int i = t; i < NPB; i += 256) deg[i] = 0;
  __syncthreads();
  for (int i = t; i < nv; i += 256) {
    int4 p4 = eb4[i];
    atomicAdd(&deg[((unsigned)p4.x) >> 18], 1);
    atomicAdd(&deg[((unsigned)p4.y) >> 18], 1);
    atomicAdd(&deg[((unsigned)p4.z) >> 18], 1);
    atomicAdd(&deg[((unsigned)p4.w) >> 18], 1);
  }
  for (int i = estart + (nv << 2) + t; i < eend; i += 256) {
    int p = ebuf[i];
    atomicAdd(&deg[((unsigned)p) >> 18], 1);
  }
  __syncthreads();
  int d0 = deg[t * 4], d1 = deg[t * 4 + 1], d2 = deg[t * 4 + 2], d3 = deg[t * 4 + 3];
  int tsum = d0 + d1 + d2 + d3;
  int incl = tsum;
  #pragma unroll
  for (int off = 1; off < 64; off <<= 1) {
    int u = __shfl_up(incl, off);
    if (lane >= off) incl += u;
  }
  if (lane == 63) wsum[wid] = incl;
  int wexcl = incl - tsum;
  __syncthreads();
  int wbase = 0;
  for (int w = 0; w < wid; ++w) wbase += wsum[w];
  int ebase = wbase + wexcl;
  cur[t * 4 + 0] = ebase;
  cur[t * 4 + 1] = ebase + d0;
  cur[t * 4 + 2] = ebase + d0 + d1;
  cur[t * 4 + 3] = ebase + d0 + d1 + d2;
  __syncthreads();
  #pragma unroll
  for (int k = 0; k < 4; ++k) {
    int dl = t * 4 + k;
    int n = b * NPB + dl;
    if (n < N_NODES) {
      rowstart[n] = estart + cur[dl];
      rowlen[n] = deg[dl];
      float dv = rsqrtf((float)(deg[dl] + 1));
      dinv[n] = dv;
      float4 v;
      v.x = x[n * 3 + 0] * dv;
      v.y = x[n * 3 + 1] * dv;
      v.z = x[n * 3 + 2] * dv;
      v.w = 0.f;
      xs[n] = v;
    }
  }
  __syncthreads();
  for (int i = t; i < nv; i += 256) {
    int4 p4 = eb4[i];
    #pragma unroll
    for (int c = 0; c < 4; ++c) {
      int p = (&p4.x)[c];
      int dl = ((unsigned)p) >> 18;
      int lpos = atomicAdd(&cur[dl], 1);
      cols[estart + lpos] = p & 0x3FFFF;
    }
  }
  for (int i = estart + (nv << 2) + t; i < eend; i += 256) {
    int p = ebuf[i];
    int dl = ((unsigned)p) >> 18;
    int lpos = atomicAdd(&cur[dl], 1);
    cols[estart + lpos] = p & 0x3FFFF;
  }
}

// ---------------- layer-1: aggregate 3-feature x + fused 3x3 moments ----------------

__global__ void k_agg1(const float4* __restrict__ xs, float4* __restrict__ t,
                       const int* __restrict__ rowstart, const int* __restrict__ rowlen,
                       const int* __restrict__ cols,
                       const float* __restrict__ dinv, float* __restrict__ mom) {
  int n = blockIdx.x * blockDim.x + threadIdx.x;
  float m9[9] = {0.f, 0.f, 0.f, 0.f, 0.f, 0.f, 0.f, 0.f, 0.f};
  if (n < N_NODES) {
    float4 self = xs[n];
    float a0 = self.x, a1 = self.y, a2 = self.z;
    float b0 = 0.f, b1 = 0.f, b2 = 0.f;
    float c0 = 0.f, c1 = 0.f, c2 = 0.f;
    float e0 = 0.f, e1 = 0.f, e2 = 0.f;
    int base = rowstart[n];
    int len = rowlen[n];
    int j = 0;
    for (; j + 8 <= len; j += 8) {   // 8 float4 loads in flight
      int s0 = cols[base + j],     s1 = cols[base + j + 1];
      int s2 = cols[base + j + 2], s3 = cols[base + j + 3];
      int s4 = cols[base + j + 4], s5 = cols[base + j + 5];
      int s6 = cols[base + j + 6], s7 = cols[base + j + 7];
      float4 v0 = xs[s0], v1 = xs[s1], v2 = xs[s2], v3 = xs[s3];
      float4 v4 = xs[s4], v5 = xs[s5], v6 = xs[s6], v7 = xs[s7];
      a0 += v0.x + v4.x; a1 += v0.y + v4.y; a2 += v0.z + v4.z;
      b0 += v1.x + v5.x; b1 += v1.y + v5.y; b2 += v1.z + v5.z;
      c0 += v2.x + v6.x; c1 += v2.y + v6.y; c2 += v2.z + v6.z;
      e0 += v3.x + v7.x; e1 += v3.y + v7.y; e2 += v3.z + v7.z;
    }
    for (; j + 4 <= len; j += 4) {
      int s0 = cols[base + j], s1 = cols[base + j + 1];
      int s2 = cols[base + j + 2], s3 = cols[base + j + 3];
      float4 v0 = xs[s0], v1 = xs[s1], v2 = xs[s2], v3 = xs[s3];
      a0 += v0.x; a1 += v0.y; a2 += v0.z;
      b0 += v1.x; b1 += v1.y; b2 += v1.z;
      c0 += v2.x; c1 += v2.y; c2 += v2.z;
      e0 += v3.x; e1 += v3.y; e2 += v3.z;
    }
    for (; j < len; ++j) {
      float4 v = xs[cols[base + j]];
      a0 += v.x; a1 += v.y; a2 += v.z;
    }
    float dv = dinv[n];
    float4 o;
    o.x = dv * ((a0 + b0) + (c0 + e0));
    o.y = dv * ((a1 + b1) + (c1 + e1));
    o.z = dv * ((a2 + b2) + (c2 + e2));
    o.w = 0.f;
    t[n] = o;
    m9[0] = o.x; m9[1] = o.y; m9[2] = o.z;
    m9[3] = o.x * o.x; m9[4] = o.x * o.y; m9[5] = o.x * o.z;
    m9[6] = o.y * o.y; m9[7] = o.y * o.z; m9[8] = o.z * o.z;
  }
  #pragma unroll
  for (int off = 32; off; off >>= 1) {
    #pragma unroll
    for (int i = 0; i < 9; ++i) m9[i] += __shfl_xor(m9[i], off);
  }
  __shared__ float ls[4][9];
  int lane = threadIdx.x & 63, wid = threadIdx.x >> 6;
  if (lane == 0) {
    #pragma unroll
    for (int i = 0; i < 9; ++i) ls[wid][i] = m9[i];
  }
  __syncthreads();
  if (threadIdx.x < 9) {
    float s = ls[0][threadIdx.x] + ls[1][threadIdx.x] + ls[2][threadIdx.x] + ls[3][threadIdx.x];
    atomicAdd(&mom[threadIdx.x], s);
  }
}

// fused layer-2 front end: h1 = t @ W1 (in-register), BN1 (stats from moments),
// relu, @W2 via split-bf16 MFMA, scale by dinv -> hb (bf16 only)
__global__ void __launch_bounds__(256) k_l2m2(const float4* __restrict__ t,
                                              ushort_t* __restrict__ hb,
                                              const float* __restrict__ W1,
                                              const float* __restrict__ W2,
                                              const float* __restrict__ mom,
                                              const float* __restrict__ gamma,
                                              const float* __restrict__ beta,
                                              const float* __restrict__ dinv) {
  __shared__ float w1s[192];
  __shared__ ushort_t w2t_hi[64 * 64];   // [out_feat][k]
  __shared__ ushort_t w2t_lo[64 * 64];
  __shared__ float tt[4][16][4];
  __shared__ ushort_t at_hi[4][16 * 64];
  __shared__ ushort_t at_lo[4][16 * 64];
  int tix = threadIdx.x;
  int lane = tix & 63, wid = tix >> 6;
  if (tix < 192) w1s[tix] = W1[tix];
  for (int i = tix; i < 64 * 64; i += 256) {
    int f = i >> 6, k = i & 63;
    float w = W2[k * 64 + f];
    ushort_t hi = f32_to_bf16(w);
    w2t_hi[i] = hi;
    w2t_lo[i] = f32_to_bf16(w - bf16_to_f32(hi));
  }
  __syncthreads();

  int col = lane & 15, kb = lane >> 4;
  short8 bhi[4][2], blo[4][2];
  #pragma unroll
  for (int nt = 0; nt < 4; ++nt) {
    #pragma unroll
    for (int ks = 0; ks < 2; ++ks) {
      int base = (nt * 16 + col) * 64 + ks * 32 + kb * 8;
      bhi[nt][ks] = *reinterpret_cast<const short8*>(&w2t_hi[base]);
      blo[nt][ks] = *reinterpret_cast<const short8*>(&w2t_lo[base]);
    }
  }

  float inv_n = 1.0f / N_NODES;
  float w0 = w1s[lane], w1 = w1s[64 + lane], w2 = w1s[128 + lane];
  float mu = (mom[0] * w0 + mom[1] * w1 + mom[2] * w2) * inv_n;
  float eh2 = (mom[3] * w0 * w0 + 2.f * mom[4] * w0 * w1 + 2.f * mom[5] * w0 * w2 +
               mom[6] * w1 * w1 + 2.f * mom[7] * w1 * w2 + mom[8] * w2 * w2) * inv_n;
  float var = eh2 - mu * mu;
  float sc = rsqrtf(var + EPS) * gamma[lane];
  float sh = beta[lane] - mu * sc;

  for (int bt = blockIdx.x; bt < 3125; bt += gridDim.x) {
    int n0 = (bt * 4 + wid) * 16;
    if (lane < 16) {
      float4 v = t[n0 + lane];
      tt[wid][lane][0] = v.x; tt[wid][lane][1] = v.y; tt[wid][lane][2] = v.z;
    }
    #pragma unroll 4
    for (int i = 0; i < 16; ++i) {
      float h = tt[wid][i][0] * w0 + tt[wid][i][1] * w1 + tt[wid][i][2] * w2;
      float a = h * sc + sh;
      a = a > 0.f ? a : 0.f;
      ushort_t hi = f32_to_bf16(a);
      at_hi[wid][i * 64 + lane] = hi;
      at_lo[wid][i * 64 + lane] = f32_to_bf16(a - bf16_to_f32(hi));
    }
    short8 ahi[2], alo[2];
    #pragma unroll
    for (int ks = 0; ks < 2; ++ks) {
      int base = col * 64 + ks * 32 + kb * 8;   // A: row=lane&15, k-block
      ahi[ks] = *reinterpret_cast<const short8*>(&at_hi[wid][base]);
      alo[ks] = *reinterpret_cast<const short8*>(&at_lo[wid][base]);
    }
    float dv[4];
    #pragma unroll
    for (int r = 0; r < 4; ++r) dv[r] = dinv[n0 + kb * 4 + r];

    #pragma unroll
    for (int nt = 0; nt < 4; ++nt) {
      f32x4 acc = {0.f, 0.f, 0.f, 0.f};
      #pragma unroll
      for (int ks = 0; ks < 2; ++ks) {
        acc = __builtin_amdgcn_mfma_f32_16x16x32_bf16(ahi[ks], bhi[nt][ks], acc, 0, 0, 0);
        acc = __builtin_amdgcn_mfma_f32_16x16x32_bf16(ahi[ks], blo[nt][ks], acc, 0, 0, 0);
        acc = __builtin_amdgcn_mfma_f32_16x16x32_bf16(alo[ks], bhi[nt][ks], acc, 0, 0, 0);
      }
      #pragma unroll
      for (int r = 0; r < 4; ++r) {
        int node = n0 + kb * 4 + r;      // C/D: row=(lane>>4)*4+r, col=lane&15
        int feat = nt * 16 + col;
        hb[node * 64 + feat] = f32_to_bf16(acc[r] * dv[r]);
      }
    }
  }
}

// layer-2 aggregation: one node per wave; uint4 gather (8 lanes span a 128B row,
// 8 neighbors per load instruction, 4 loads in flight = 32 neighbors/group).
__global__ void k_agg2(const ushort_t* __restrict__ hb, ushort_t* __restrict__ h1b,
                       const int* __restrict__ rowstart, const int* __restrict__ rowlen,
                       const int* __restrict__ cols, const float* __restrict__ dinv) {
  int node = blockIdx.x * 4 + (threadIdx.x >> 6);
  int lane = threadIdx.x & 63;
  if (node >= N_NODES) return;
  int g8 = lane >> 3;        // neighbor sub-group 0..7
  int fe = lane & 7;         // uint4 index within row (features 8*fe .. 8*fe+7)
  const uint4* hb4 = (const uint4*)hb;   // 8 uint4 per node row
  float a0, a1, a2, a3, a4, a5, a6, a7;
  if (g8 == 0) {             // self loop (bf16)
    uint4 u = hb4[node * 8 + fe];
    a0 = bfu_lo(u.x); a1 = bfu_hi(u.x); a2 = bfu_lo(u.y); a3 = bfu_hi(u.y);
    a4 = bfu_lo(u.z); a5 = bfu_hi(u.z); a6 = bfu_lo(u.w); a7 = bfu_hi(u.w);
  } else {
    a0 = a1 = a2 = a3 = a4 = a5 = a6 = a7 = 0.f;
  }
  int base = rowstart[node];
  int len = rowlen[node];
  for (int c0 = 0; c0 < len; c0 += 64) {
    int rem = len - c0;
    int m = rem < 64 ? rem : 64;
    int cidx = (lane < m) ? cols[base + c0 + lane] : 0;
    int j = 0;
    for (; j + 32 <= m; j += 32) {   // 32 neighbors: 4 uint4 loads in flight per lane
      int sA = __shfl(cidx, j + g8);
      int sB = __shfl(cidx, j + 8 + g8);
      int sC = __shfl(cidx, j + 16 + g8);
      int sD = __shfl(cidx, j + 24 + g8);
      uint4 uA = hb4[sA * 8 + fe], uB = hb4[sB * 8 + fe];
      uint4 uC = hb4[sC * 8 + fe], uD = hb4[sD * 8 + fe];
      a0 += (bfu_lo(uA.x) + bfu_lo(uB.x)) + (bfu_lo(uC.x) + bfu_lo(uD.x));
      a1 += (bfu_hi(uA.x) + bfu_hi(uB.x)) + (bfu_hi(uC.x) + bfu_hi(uD.x));
      a2 += (bfu_lo(uA.y) + bfu_lo(uB.y)) + (bfu_lo(uC.y) + bfu_lo(uD.y));
      a3 += (bfu_hi(uA.y) + bfu_hi(uB.y)) + (bfu_hi(uC.y) + bfu_hi(uD.y));
      a4 += (bfu_lo(uA.z) + bfu_lo(uB.z)) + (bfu_lo(uC.z) + bfu_lo(uD.z));
      a5 += (bfu_hi(uA.z) + bfu_hi(uB.z)) + (bfu_hi(uC.z) + bfu_hi(uD.z));
      a6 += (bfu_lo(uA.w) + bfu_lo(uB.w)) + (bfu_lo(uC.w) + bfu_lo(uD.w));
      a7 += (bfu_hi(uA.w) + bfu_hi(uB.w)) + (bfu_hi(uC.w) + bfu_hi(uD.w));
    }
    for (; j + 8 <= m; j += 8) {     // 8 neighbors: 1 load per lane
      int s = __shfl(cidx, j + g8);
      uint4 u = hb4[s * 8 + fe];
      a0 += bfu_lo(u.x); a1 += bfu_hi(u.x); a2 += bfu_lo(u.y); a3 += bfu_hi(u.y);
      a4 += bfu_lo(u.z); a5 += bfu_hi(u.z); a6 += bfu_lo(u.w); a7 += bfu_hi(u.w);
    }
    for (; j < m; ++j) {             // tail: group 0 only
      int s = __shfl(cidx, j);
      if (g8 == 0) {
        uint4 u = hb4[s * 8 + fe];
        a0 += bfu_lo(u.x); a1 += bfu_hi(u.x); a2 += bfu_lo(u.y); a3 += bfu_hi(u.y);
        a4 += bfu_lo(u.z); a5 += bfu_hi(u.z); a6 += bfu_lo(u.w); a7 += bfu_hi(u.w);
      }
    }
  }
  // reduce across the 8 neighbor sub-groups (lane bits 3..5)
  #pragma unroll
  for (int off = 8; off <= 32; off <<= 1) {
    a0 += __shfl_xor(a0, off); a1 += __shfl_xor(a1, off);
    a2 += __shfl_xor(a2, off); a3 += __shfl_xor(a3, off);
    a4 += __shfl_xor(a4, off); a5 += __shfl_xor(a5, off);
    a6 += __shfl_xor(a6, off); a7 += __shfl_xor(a7, off);
  }
  if (lane < 8) {
    float dv = dinv[node];
    a0 *= dv; a1 *= dv; a2 *= dv; a3 *= dv;
    a4 *= dv; a5 *= dv; a6 *= dv; a7 *= dv;
    uint4 o;
    o.x = ((unsigned)f32_to_bf16(a1) << 16) | (unsigned)f32_to_bf16(a0);
    o.y = ((unsigned)f32_to_bf16(a3) << 16) | (unsigned)f32_to_bf16(a2);
    o.z = ((unsigned)f32_to_bf16(a5) << 16) | (unsigned)f32_to_bf16(a4);
    o.w = ((unsigned)f32_to_bf16(a7) << 16) | (unsigned)f32_to_bf16(a6);
    ((uint4*)h1b)[node * 8 + fe] = o;
  }
}

// BN2 stats from packed bf16 h1 -> stats[0:64], stats[64:128]
__global__ void k_bnstats_b(const ushort_t* __restrict__ h1b, float* __restrict__ stats) {
  const unsigned* h32 = (const unsigned*)h1b;
  int tid = threadIdx.x;
  int lane = tid & 63, wid = tid >> 6;
  int fl = lane & 31, rsel = lane >> 5;
  float s0 = 0.f, s1 = 0.f, q0 = 0.f, q1 = 0.f;
  for (int r = blockIdx.x * 8 + wid * 2 + rsel; r < N_NODES; r += gridDim.x * 8) {
    unsigned u = h32[r * 32 + fl];
    float a = bfu_lo(u), b = bfu_hi(u);
    s0 += a; s1 += b; q0 += a * a; q1 += b * b;
  }
  s0 += __shfl_xor(s0, 32); s1 += __shfl_xor(s1, 32);
  q0 += __shfl_xor(q0, 32); q1 += __shfl_xor(q1, 32);
  __shared__ float ls[4][64], lq[4][64];
  if (rsel == 0) {
    ls[wid][2 * fl] = s0; ls[wid][2 * fl + 1] = s1;
    lq[wid][2 * fl] = q0; lq[wid][2 * fl + 1] = q1;
  }
  __syncthreads();
  if (tid < 64) {
    float a = ls[0][tid] + ls[1][tid] + ls[2][tid] + ls[3][tid];
    float b = lq[0][tid] + lq[1][tid] + lq[2][tid] + lq[3][tid];
    atomicAdd(&stats[tid], a);
    atomicAdd(&stats[64 + tid], b);
  }
}

// ---------------- pooling + head ----------------

__global__ void k_gstart(const int* __restrict__ batch, int* __restrict__ gstart) {
  int g = blockIdx.x * blockDim.x + threadIdx.x;
  if (g > N_GRAPHS) return;
  int lo = 0, hi = N_NODES;
  while (lo < hi) {
    int mid = (lo + hi) >> 1;
    if (batch[mid] < g) lo = mid + 1; else hi = mid;
  }
  gstart[g] = lo;
}

__global__ void k_pool(const ushort_t* __restrict__ h1b, const float* __restrict__ stats2,
                       const float* __restrict__ gamma, const float* __restrict__ beta,
                       const int* __restrict__ gstart, float* __restrict__ hgraph) {
  __shared__ float ssum[4][64], smax[4][64];
  int g = blockIdx.x;
  int lane = threadIdx.x & 63, wid = threadIdx.x >> 6;
  int s0 = gstart[g], s1 = gstart[g + 1];
  float mu = stats2[lane] * (1.0f / N_NODES);
  float var = stats2[64 + lane] * (1.0f / N_NODES) - mu * mu;
  float sc = rsqrtf(var + EPS) * gamma[lane];
  float sh = beta[lane] - mu * sc;
  float sum = 0.f, mx = 0.f;
  for (int r = s0 + wid; r < s1; r += 4) {
    float v = bf16_to_f32(h1b[r * 64 + lane]) * sc + sh;
    v = v > 0.f ? v : 0.f;
    sum += v;
    mx = v > mx ? v : mx;
  }
  ssum[wid][lane] = sum;
  smax[wid][lane] = mx;
  __syncthreads();
  if (wid == 0) {
    float s = ssum[0][lane] + ssum[1][lane] + ssum[2][lane] + ssum[3][lane];
    float m = fmaxf(fmaxf(smax[0][lane], smax[1][lane]), fmaxf(smax[2][lane], smax[3][lane]));
    int cnt = s1 - s0;
    float inv = 1.0f / (float)(cnt > 0 ? cnt : 1);
    hgraph[g * 128 + lane] = s * inv;
    hgraph[g * 128 + 64 + lane] = m;
  }
}

__global__ void k_head(const float* __restrict__ hgraph,
                       const float* __restrict__ emb, const int* __restrict__ recipe,
                       const float* __restrict__ conv_w, const float* __restrict__ conv_b,
                       const float* __restrict__ fc_w, const float* __restrict__ fc_b,
                       const float* __restrict__ m1_w, const float* __restrict__ m1_b,
                       const float* __restrict__ m2_w, const float* __restrict__ m2_b,
                       const float* __restrict__ m3_w, const float* __restrict__ m3_b,
                       float* __restrict__ out) {
  __shared__ float r_s[RLEN][EMBED];
  __shared__ float convout[16 * RLEN];
  __shared__ float cvec[192];
  __shared__ float y1[128];
  __shared__ float y2[64];
  __shared__ int rec_s[RLEN];
  __shared__ float emb_s[80];
  int g = blockIdx.x;
  int t = threadIdx.x;
  if (t < 80) emb_s[t] = emb[t];
  if (t < RLEN) rec_s[t] = recipe[g * RLEN + t];
  __syncthreads();
  for (int idx = t; idx < RLEN * EMBED; idx += blockDim.x) {
    int pos = idx >> 3, e = idx & 7;
    r_s[pos][e] = emb_s[rec_s[pos] * EMBED + e];
  }
  if (t < 128) cvec[t] = hgraph[g * 128 + t];
  __syncthreads();
  for (int idx = t; idx < 16 * RLEN; idx += blockDim.x) {
    int c = idx / RLEN, pos = idx % RLEN;
    float acc = conv_b[c];
    #pragma unroll
    for (int k = 0; k < 3; ++k) {
      int p = pos + k - 1;
      if (p >= 0 && p < RLEN) {
        #pragma unroll
        for (int e = 0; e < EMBED; ++e)
          acc = fmaf(r_s[p][e], conv_w[(c * EMBED + e) * 3 + k], acc);
      }
    }
    convout[c * RLEN + pos] = acc > 0.f ? acc : 0.f;
  }
  __syncthreads();
  if (t < 64) {
    float acc = fc_b[t];
    for (int i = 0; i < 320; ++i) acc = fmaf(convout[i], fc_w[i * 64 + t], acc);
    cvec[128 + t] = acc > 0.f ? acc : 0.f;
  }
  __syncthreads();
  if (t < 128) {
    float acc = m1_b[t];
    for (int i = 0; i < 192; ++i) acc = fmaf(cvec[i], m1_w[i * 128 + t], acc);
    y1[t] = acc > 0.f ? acc : 0.f;
  }
  __syncthreads();
  if (t < 64) {
    float acc = m2_b[t];
    for (int i = 0; i < 128; ++i) acc = fmaf(y1[i], m2_w[i * 64 + t], acc);
    y2[t] = acc > 0.f ? acc : 0.f;
  }
  __syncthreads();
  if (t < 3) {
    float acc = m3_b[t];
    for (int i = 0; i < 64; ++i) acc = fmaf(y2[i], m3_w[i * 3 + t], acc);
    out[g * 3 + t] = acc;
  }
}

extern "C" void kernel_launch(void* const* d_in, const int* in_sizes, int n_in,
                              void* d_out, int out_size, void* d_ws, size_t ws_size,
                              hipStream_t stream) {
  const float* x      = (const float*)d_in[0];
  const float* W1     = (const float*)d_in[1];
  // b1 (d_in[2]) cancels under BN
  const float* gamma1 = (const float*)d_in[3];
  const float* beta1  = (const float*)d_in[4];
  const float* W2     = (const float*)d_in[5];
  // b2 (d_in[6]) cancels under BN
  const float* gamma2 = (const float*)d_in[7];
  const float* beta2  = (const float*)d_in[8];
  const float* emb    = (const float*)d_in[9];
  const float* conv_w = (const float*)d_in[10];
  const float* conv_b = (const float*)d_in[11];
  const float* fc_w   = (const float*)d_in[12];
  const float* fc_b   = (const float*)d_in[13];
  const float* m1_w   = (const float*)d_in[14];
  const float* m1_b   = (const float*)d_in[15];
  const float* m2_w   = (const float*)d_in[16];
  const float* m2_b   = (const float*)d_in[17];
  const float* m3_w   = (const float*)d_in[18];
  const float* m3_b   = (const float*)d_in[19];
  const int* ei       = (const int*)d_in[20];
  const int* batch    = (const int*)d_in[21];
  const int* recipe   = (const int*)d_in[22];
  const int* e_src = ei;
  const int* e_dst = ei + N_EDGES;
  float* out = (float*)d_out;

  char* p = (char*)d_ws;
  auto alloc = [&](size_t bytes) {
    char* r = p;
    p += (bytes + 255) & ~(size_t)255;
    return (void*)r;
  };
  int*   bcursor  = (int*)alloc((size_t)NBKT * 4);
  float* dinv     = (float*)alloc((size_t)N_NODES * 4);
  int*   rowstart = (int*)alloc((size_t)N_NODES * 4);
  int*   rowlen   = (int*)alloc((size_t)N_NODES * 4);
  int*   gstart   = (int*)alloc((size_t)(N_GRAPHS + 1) * 4);
  float* stats    = (float*)alloc(256 * 4);
  float* mom      = (float*)alloc(16 * 4);
  float* hgraph   = (float*)alloc((size_t)N_GRAPHS * 128 * 4);
  int*   cols     = (int*)alloc((size_t)NBKT * CAP * 4);
  float4* xs      = (float4*)alloc((size_t)N_NODES * 16);
  float4* tbuf    = (float4*)alloc((size_t)N_NODES * 16);
  int*   ebuf     = (int*)alloc((size_t)NBKT * CAP * 4);
  ushort_t* hb    = (ushort_t*)alloc((size_t)N_NODES * 64 * 2);
  ushort_t* h1b   = (ushort_t*)ebuf;  // alias: ebuf dead before k_agg2 writes h1b

  hipMemsetAsync(stats, 0, 256 * 4, stream);
  hipMemsetAsync(mom, 0, 16 * 4, stream);

  k_binit<<<1, 256, 0, stream>>>(bcursor);
  k_bscatter<<<(N_EDGES + CHUNK - 1) / CHUNK, 256, 0, stream>>>(e_src, e_dst, bcursor, ebuf);
  k_bfill<<<NBKT, 256, 0, stream>>>(bcursor, ebuf, x, rowstart, rowlen, dinv, xs, cols);
  k_agg1<<<(N_NODES + 255) / 256, 256, 0, stream>>>(xs, tbuf, rowstart, rowlen, cols, dinv, mom);
  k_l2m2<<<625, 256, 0, stream>>>(tbuf, hb, W1, W2, mom, gamma1, beta1, dinv);
  k_agg2<<<(N_NODES + 3) / 4, 256, 0, stream>>>(hb, h1b, rowstart, rowlen, cols, dinv);
  k_bnstats_b<<<512, 256, 0, stream>>>(h1b, stats);
  k_gstart<<<1, 576, 0, stream>>>(batch, gstart);
  k_pool<<<N_GRAPHS, 256, 0, stream>>>(h1b, stats, gamma2, beta2, gstart, hgraph);
  k_head<<<N_GRAPHS, 128, 0, stream>>>(hgraph, emb, recipe, conv_w, conv_b, fc_w, fc_b,
                                       m1_w, m1_b, m2_w, m2_b, m3_w, m3_b, out);
}

// Round 11
// 413.765 us; speedup vs baseline: 1.0773x; 1.0773x over previous
//
#include <hip/hip_runtime.h>

#define N_NODES 200000
#define N_EDGES 6400000
#define N_GRAPHS 512
#define RLEN 20
#define EMBED 8
#define EPS 1e-5f

#define NPB 1024                           // nodes per bucket
#define NBKT ((N_NODES + NPB - 1) / NPB)   // 196
#define CHUNK 8192                         // edges per k_bscatter block (512 thr x 16)
#define CAP 36864                          // padded bucket capacity (mean 32653 + 23 sigma)

typedef unsigned short ushort_t;
typedef __attribute__((ext_vector_type(8))) short short8;
typedef __attribute__((ext_vector_type(4))) float f32x4;

__device__ inline ushort_t f32_to_bf16(float f) {
  unsigned u = __float_as_uint(f);
  unsigned r = (u + 0x7fff + ((u >> 16) & 1)) >> 16;  // RNE
  return (ushort_t)r;
}
__device__ inline float bf16_to_f32(ushort_t us) {
  return __uint_as_float(((unsigned)us) << 16);
}
__device__ inline float bfu_lo(unsigned u) { return __uint_as_float(u << 16); }
__device__ inline float bfu_hi(unsigned u) { return __uint_as_float(u & 0xFFFF0000u); }

// ---------------- bucketed CSR build (padded buckets; direct-write scatter) ----------------
// bcursor[b] holds COUNT (memset 0); ebuf slot = b*CAP + rank.

__global__ void __launch_bounds__(512) k_bscatter(const int* __restrict__ src,
                                                  const int* __restrict__ dst,
                                                  int* __restrict__ bcursor,
                                                  int* __restrict__ ebuf) {
  __shared__ int hist[256];
  __shared__ int gbase[256];
  int t = threadIdx.x;
  if (t < 256) hist[t] = 0;
  __syncthreads();

  const int4* src4 = (const int4*)(src + blockIdx.x * CHUNK);
  const int4* dst4 = (const int4*)(dst + blockIdx.x * CHUNK);
  int e0 = blockIdx.x * CHUNK;
  int nrem = N_EDGES - e0;
  int nv = (nrem >= CHUNK ? CHUNK : nrem) >> 2;     // int4 groups (N_EDGES%4==0)

  int pk[16], bk[16], rk[16];
  #pragma unroll
  for (int g = 0; g < 4; ++g) {
    int vi = g * 512 + t;
    if (vi < nv) {
      int4 s4 = src4[vi];
      int4 d4 = dst4[vi];
      #pragma unroll
      for (int c = 0; c < 4; ++c) {
        int s = (&s4.x)[c], d = (&d4.x)[c];
        int b = d >> 10;
        pk[g * 4 + c] = s | ((d & (NPB - 1)) << 18);
        bk[g * 4 + c] = b;
        rk[g * 4 + c] = atomicAdd(&hist[b], 1);
      }
    } else {
      #pragma unroll
      for (int c = 0; c < 4; ++c) bk[g * 4 + c] = -1;
    }
  }
  __syncthreads();
  if (t < NBKT && hist[t] > 0) gbase[t] = t * CAP + atomicAdd(&bcursor[t], hist[t]);
  __syncthreads();
  #pragma unroll
  for (int k = 0; k < 16; ++k) {
    if (bk[k] >= 0) ebuf[gbase[bk[k]] + rk[k]] = pk[k];
  }
}

// per bucket: degrees -> rowstart/rowlen/dinv/xs, then local scatter of cols
__global__ void __launch_bounds__(256) k_bfill(const int* __restrict__ bcursor,
                                               const int* __restrict__ ebuf,
                                               const float* __restrict__ x,
                                               int* __restrict__ rowstart,
                                               int* __restrict__ rowlen,
                                               float* __restrict__ dinv,
                                               float4* __restrict__ xs,
                                               int* __restrict__ cols) {
  __shared__ int deg[NPB];
  __shared__ int cur[NPB];
  __shared__ int wsum[4];
  int b = blockIdx.x;
  int t = threadIdx.x;
  int lane = t & 63, wid = t >> 6;
  int estart = b * CAP;
  int cnt = bcursor[b];
  int eend = estart + cnt;
  int nv = cnt >> 2;
  const int4* eb4 = (const int4*)(ebuf + estart);   // estart % 4 == 0
  for (int i = t; i < NPB; i += 256) deg[i] = 0;
  __syncthreads();
  for (int i = t; i < nv; i += 256) {
    int4 p4 = eb4[i];
    atomicAdd(&deg[((unsigned)p4.x) >> 18], 1);
    atomicAdd(&deg[((unsigned)p4.y) >> 18], 1);
    atomicAdd(&deg[((unsigned)p4.z) >> 18], 1);
    atomicAdd(&deg[((unsigned)p4.w) >> 18], 1);
  }
  for (int i = estart + (nv << 2) + t; i < eend; i += 256) {
    int p = ebuf[i];
    atomicAdd(&deg[((unsigned)p) >> 18], 1);
  }
  __syncthreads();
  int d0 = deg[t * 4], d1 = deg[t * 4 + 1], d2 = deg[t * 4 + 2], d3 = deg[t * 4 + 3];
  int tsum = d0 + d1 + d2 + d3;
  int incl = tsum;
  #pragma unroll
  for (int off = 1; off < 64; off <<= 1) {
    int u = __shfl_up(incl, off);
    if (lane >= off) incl += u;
  }
  if (lane == 63) wsum[wid] = incl;
  int wexcl = incl - tsum;
  __syncthreads();
  int wbase = 0;
  for (int w = 0; w < wid; ++w) wbase += wsum[w];
  int ebase = wbase + wexcl;
  cur[t * 4 + 0] = ebase;
  cur[t * 4 + 1] = ebase + d0;
  cur[t * 4 + 2] = ebase + d0 + d1;
  cur[t * 4 + 3] = ebase + d0 + d1 + d2;
  __syncthreads();
  #pragma unroll
  for (int k = 0; k < 4; ++k) {
    int dl = t * 4 + k;
    int n = b * NPB + dl;
    if (n < N_NODES) {
      rowstart[n] = estart + cur[dl];
      rowlen[n] = deg[dl];
      float dv = rsqrtf((float)(deg[dl] + 1));
      dinv[n] = dv;
      float4 v;
      v.x = x[n * 3 + 0] * dv;
      v.y = x[n * 3 + 1] * dv;
      v.z = x[n * 3 + 2] * dv;
      v.w = 0.f;
      xs[n] = v;
    }
  }
  __syncthreads();
  for (int i = t; i < nv; i += 256) {
    int4 p4 = eb4[i];
    #pragma unroll
    for (int c = 0; c < 4; ++c) {
      int p = (&p4.x)[c];
      int dl = ((unsigned)p) >> 18;
      int lpos = atomicAdd(&cur[dl], 1);
      cols[estart + lpos] = p & 0x3FFFF;
    }
  }
  for (int i = estart + (nv << 2) + t; i < eend; i += 256) {
    int p = ebuf[i];
    int dl = ((unsigned)p) >> 18;
    int lpos = atomicAdd(&cur[dl], 1);
    cols[estart + lpos] = p & 0x3FFFF;
  }
}

// ---------------- layer-1: aggregate 3-feature x + fused 3x3 moments ----------------

__global__ void k_agg1(const float4* __restrict__ xs, float4* __restrict__ t,
                       const int* __restrict__ rowstart, const int* __restrict__ rowlen,
                       const int* __restrict__ cols,
                       const float* __restrict__ dinv, float* __restrict__ mom) {
  int n = blockIdx.x * blockDim.x + threadIdx.x;
  float m9[9] = {0.f, 0.f, 0.f, 0.f, 0.f, 0.f, 0.f, 0.f, 0.f};
  if (n < N_NODES) {
    float4 self = xs[n];
    float a0 = self.x, a1 = self.y, a2 = self.z;
    float b0 = 0.f, b1 = 0.f, b2 = 0.f;
    float c0 = 0.f, c1 = 0.f, c2 = 0.f;
    float e0 = 0.f, e1 = 0.f, e2 = 0.f;
    int base = rowstart[n];
    int len = rowlen[n];
    int j = 0;
    for (; j + 8 <= len; j += 8) {   // 8 float4 loads in flight
      int s0 = cols[base + j],     s1 = cols[base + j + 1];
      int s2 = cols[base + j + 2], s3 = cols[base + j + 3];
      int s4 = cols[base + j + 4], s5 = cols[base + j + 5];
      int s6 = cols[base + j + 6], s7 = cols[base + j + 7];
      float4 v0 = xs[s0], v1 = xs[s1], v2 = xs[s2], v3 = xs[s3];
      float4 v4 = xs[s4], v5 = xs[s5], v6 = xs[s6], v7 = xs[s7];
      a0 += v0.x + v4.x; a1 += v0.y + v4.y; a2 += v0.z + v4.z;
      b0 += v1.x + v5.x; b1 += v1.y + v5.y; b2 += v1.z + v5.z;
      c0 += v2.x + v6.x; c1 += v2.y + v6.y; c2 += v2.z + v6.z;
      e0 += v3.x + v7.x; e1 += v3.y + v7.y; e2 += v3.z + v7.z;
    }
    for (; j + 4 <= len; j += 4) {
      int s0 = cols[base + j], s1 = cols[base + j + 1];
      int s2 = cols[base + j + 2], s3 = cols[base + j + 3];
      float4 v0 = xs[s0], v1 = xs[s1], v2 = xs[s2], v3 = xs[s3];
      a0 += v0.x; a1 += v0.y; a2 += v0.z;
      b0 += v1.x; b1 += v1.y; b2 += v1.z;
      c0 += v2.x; c1 += v2.y; c2 += v2.z;
      e0 += v3.x; e1 += v3.y; e2 += v3.z;
    }
    for (; j < len; ++j) {
      float4 v = xs[cols[base + j]];
      a0 += v.x; a1 += v.y; a2 += v.z;
    }
    float dv = dinv[n];
    float4 o;
    o.x = dv * ((a0 + b0) + (c0 + e0));
    o.y = dv * ((a1 + b1) + (c1 + e1));
    o.z = dv * ((a2 + b2) + (c2 + e2));
    o.w = 0.f;
    t[n] = o;
    m9[0] = o.x; m9[1] = o.y; m9[2] = o.z;
    m9[3] = o.x * o.x; m9[4] = o.x * o.y; m9[5] = o.x * o.z;
    m9[6] = o.y * o.y; m9[7] = o.y * o.z; m9[8] = o.z * o.z;
  }
  #pragma unroll
  for (int off = 32; off; off >>= 1) {
    #pragma unroll
    for (int i = 0; i < 9; ++i) m9[i] += __shfl_xor(m9[i], off);
  }
  __shared__ float ls[4][9];
  int lane = threadIdx.x & 63, wid = threadIdx.x >> 6;
  if (lane == 0) {
    #pragma unroll
    for (int i = 0; i < 9; ++i) ls[wid][i] = m9[i];
  }
  __syncthreads();
  if (threadIdx.x < 9) {
    float s = ls[0][threadIdx.x] + ls[1][threadIdx.x] + ls[2][threadIdx.x] + ls[3][threadIdx.x];
    atomicAdd(&mom[threadIdx.x], s);
  }
}

// fused layer-2 front end: h1 = t @ W1 (in-register), BN1 (stats from moments),
// relu, @W2 via split-bf16 MFMA, scale by dinv -> hb (bf16 only)
__global__ void __launch_bounds__(256) k_l2m2(const float4* __restrict__ t,
                                              ushort_t* __restrict__ hb,
                                              const float* __restrict__ W1,
                                              const float* __restrict__ W2,
                                              const float* __restrict__ mom,
                                              const float* __restrict__ gamma,
                                              const float* __restrict__ beta,
                                              const float* __restrict__ dinv) {
  __shared__ float w1s[192];
  __shared__ ushort_t w2t_hi[64 * 64];   // [out_feat][k]
  __shared__ ushort_t w2t_lo[64 * 64];
  __shared__ float tt[4][16][4];
  __shared__ ushort_t at_hi[4][16 * 64];
  __shared__ ushort_t at_lo[4][16 * 64];
  int tix = threadIdx.x;
  int lane = tix & 63, wid = tix >> 6;
  if (tix < 192) w1s[tix] = W1[tix];
  for (int i = tix; i < 64 * 64; i += 256) {
    int f = i >> 6, k = i & 63;
    float w = W2[k * 64 + f];
    ushort_t hi = f32_to_bf16(w);
    w2t_hi[i] = hi;
    w2t_lo[i] = f32_to_bf16(w - bf16_to_f32(hi));
  }
  __syncthreads();

  int col = lane & 15, kb = lane >> 4;
  short8 bhi[4][2], blo[4][2];
  #pragma unroll
  for (int nt = 0; nt < 4; ++nt) {
    #pragma unroll
    for (int ks = 0; ks < 2; ++ks) {
      int base = (nt * 16 + col) * 64 + ks * 32 + kb * 8;
      bhi[nt][ks] = *reinterpret_cast<const short8*>(&w2t_hi[base]);
      blo[nt][ks] = *reinterpret_cast<const short8*>(&w2t_lo[base]);
    }
  }

  float inv_n = 1.0f / N_NODES;
  float w0 = w1s[lane], w1 = w1s[64 + lane], w2 = w1s[128 + lane];
  float mu = (mom[0] * w0 + mom[1] * w1 + mom[2] * w2) * inv_n;
  float eh2 = (mom[3] * w0 * w0 + 2.f * mom[4] * w0 * w1 + 2.f * mom[5] * w0 * w2 +
               mom[6] * w1 * w1 + 2.f * mom[7] * w1 * w2 + mom[8] * w2 * w2) * inv_n;
  float var = eh2 - mu * mu;
  float sc = rsqrtf(var + EPS) * gamma[lane];
  float sh = beta[lane] - mu * sc;

  for (int bt = blockIdx.x; bt < 3125; bt += gridDim.x) {
    int n0 = (bt * 4 + wid) * 16;
    if (lane < 16) {
      float4 v = t[n0 + lane];
      tt[wid][lane][0] = v.x; tt[wid][lane][1] = v.y; tt[wid][lane][2] = v.z;
    }
    #pragma unroll 4
    for (int i = 0; i < 16; ++i) {
      float h = tt[wid][i][0] * w0 + tt[wid][i][1] * w1 + tt[wid][i][2] * w2;
      float a = h * sc + sh;
      a = a > 0.f ? a : 0.f;
      ushort_t hi = f32_to_bf16(a);
      at_hi[wid][i * 64 + lane] = hi;
      at_lo[wid][i * 64 + lane] = f32_to_bf16(a - bf16_to_f32(hi));
    }
    short8 ahi[2], alo[2];
    #pragma unroll
    for (int ks = 0; ks < 2; ++ks) {
      int base = col * 64 + ks * 32 + kb * 8;   // A: row=lane&15, k-block
      ahi[ks] = *reinterpret_cast<const short8*>(&at_hi[wid][base]);
      alo[ks] = *reinterpret_cast<const short8*>(&at_lo[wid][base]);
    }
    float dv[4];
    #pragma unroll
    for (int r = 0; r < 4; ++r) dv[r] = dinv[n0 + kb * 4 + r];

    #pragma unroll
    for (int nt = 0; nt < 4; ++nt) {
      f32x4 acc = {0.f, 0.f, 0.f, 0.f};
      #pragma unroll
      for (int ks = 0; ks < 2; ++ks) {
        acc = __builtin_amdgcn_mfma_f32_16x16x32_bf16(ahi[ks], bhi[nt][ks], acc, 0, 0, 0);
        acc = __builtin_amdgcn_mfma_f32_16x16x32_bf16(ahi[ks], blo[nt][ks], acc, 0, 0, 0);
        acc = __builtin_amdgcn_mfma_f32_16x16x32_bf16(alo[ks], bhi[nt][ks], acc, 0, 0, 0);
      }
      #pragma unroll
      for (int r = 0; r < 4; ++r) {
        int node = n0 + kb * 4 + r;      // C/D: row=(lane>>4)*4+r, col=lane&15
        int feat = nt * 16 + col;
        hb[node * 64 + feat] = f32_to_bf16(acc[r] * dv[r]);
      }
    }
  }
}

// layer-2 aggregation (round-8 proven shape): one node per wave, dword gather,
// 8-neighbor groups (4 loads in flight per lane). Writes packed bf16 h1.
__global__ void k_agg2(const ushort_t* __restrict__ hb, ushort_t* __restrict__ h1b,
                       const int* __restrict__ rowstart, const int* __restrict__ rowlen,
                       const int* __restrict__ cols, const float* __restrict__ dinv) {
  int node = blockIdx.x * 4 + (threadIdx.x >> 6);
  int lane = threadIdx.x & 63;
  if (node >= N_NODES) return;
  int half = lane >> 5;
  int fl = lane & 31;
  const unsigned* hb32 = (const unsigned*)hb;      // hb32[s*32+fl] = feats {2fl, 2fl+1}
  unsigned* o32 = (unsigned*)h1b;
  float2 acc;
  if (half == 0) {                                  // self loop (bf16)
    unsigned u = hb32[node * 32 + fl];
    acc.x = bfu_lo(u); acc.y = bfu_hi(u);
  } else { acc.x = 0.f; acc.y = 0.f; }
  int base = rowstart[node];
  int len = rowlen[node];
  for (int c0 = 0; c0 < len; c0 += 64) {
    int rem = len - c0;
    int m = rem < 64 ? rem : 64;
    int cidx = (lane < m) ? cols[base + c0 + lane] : 0;
    int j = 0;
    for (; j + 8 <= m; j += 8) {   // 8 neighbors / iter, 4 dword loads in flight per lane
      int sA = __shfl(cidx, j + half);
      int sB = __shfl(cidx, j + 2 + half);
      int sC = __shfl(cidx, j + 4 + half);
      int sD = __shfl(cidx, j + 6 + half);
      unsigned uA = hb32[sA * 32 + fl], uB = hb32[sB * 32 + fl];
      unsigned uC = hb32[sC * 32 + fl], uD = hb32[sD * 32 + fl];
      acc.x += (bfu_lo(uA) + bfu_lo(uB)) + (bfu_lo(uC) + bfu_lo(uD));
      acc.y += (bfu_hi(uA) + bfu_hi(uB)) + (bfu_hi(uC) + bfu_hi(uD));
    }
    for (; j + 2 <= m; j += 2) {
      int s = __shfl(cidx, j + half);
      unsigned u = hb32[s * 32 + fl];
      acc.x += bfu_lo(u);
      acc.y += bfu_hi(u);
    }
    if (j < m) {                   // odd leftover: half0 only
      int s = __shfl(cidx, j);
      if (half == 0) {
        unsigned u = hb32[s * 32 + fl];
        acc.x += bfu_lo(u);
        acc.y += bfu_hi(u);
      }
    }
  }
  acc.x += __shfl_xor(acc.x, 32);
  acc.y += __shfl_xor(acc.y, 32);
  if (half == 0) {
    float dv = dinv[node];
    float ox = acc.x * dv, oy = acc.y * dv;
    o32[node * 32 + fl] = ((unsigned)f32_to_bf16(oy) << 16) | (unsigned)f32_to_bf16(ox);
  }
}

// BN2 stats from packed bf16 h1 -> stats[0:64], stats[64:128]
__global__ void k_bnstats_b(const ushort_t* __restrict__ h1b, float* __restrict__ stats) {
  const unsigned* h32 = (const unsigned*)h1b;
  int tid = threadIdx.x;
  int lane = tid & 63, wid = tid >> 6;
  int fl = lane & 31, rsel = lane >> 5;
  float s0 = 0.f, s1 = 0.f, q0 = 0.f, q1 = 0.f;
  for (int r = blockIdx.x * 8 + wid * 2 + rsel; r < N_NODES; r += gridDim.x * 8) {
    unsigned u = h32[r * 32 + fl];
    float a = bfu_lo(u), b = bfu_hi(u);
    s0 += a; s1 += b; q0 += a * a; q1 += b * b;
  }
  s0 += __shfl_xor(s0, 32); s1 += __shfl_xor(s1, 32);
  q0 += __shfl_xor(q0, 32); q1 += __shfl_xor(q1, 32);
  __shared__ float ls[4][64], lq[4][64];
  if (rsel == 0) {
    ls[wid][2 * fl] = s0; ls[wid][2 * fl + 1] = s1;
    lq[wid][2 * fl] = q0; lq[wid][2 * fl + 1] = q1;
  }
  __syncthreads();
  if (tid < 64) {
    float a = ls[0][tid] + ls[1][tid] + ls[2][tid] + ls[3][tid];
    float b = lq[0][tid] + lq[1][tid] + lq[2][tid] + lq[3][tid];
    atomicAdd(&stats[tid], a);
    atomicAdd(&stats[64 + tid], b);
  }
}

// ---------------- pooling + head ----------------

// pool with fused per-graph range search (batch is sorted)
__global__ void k_pool(const ushort_t* __restrict__ h1b, const float* __restrict__ stats2,
                       const float* __restrict__ gamma, const float* __restrict__ beta,
                       const int* __restrict__ batch, float* __restrict__ hgraph) {
  __shared__ float ssum[4][64], smax[4][64];
  __shared__ int sb[2];
  int g = blockIdx.x;
  int lane = threadIdx.x & 63, wid = threadIdx.x >> 6;
  if (threadIdx.x < 2) {
    int tg = g + threadIdx.x;
    int lo = 0, hi = N_NODES;
    while (lo < hi) {
      int mid = (lo + hi) >> 1;
      if (batch[mid] < tg) lo = mid + 1; else hi = mid;
    }
    sb[threadIdx.x] = lo;
  }
  __syncthreads();
  int s0 = sb[0], s1 = sb[1];
  float mu = stats2[lane] * (1.0f / N_NODES);
  float var = stats2[64 + lane] * (1.0f / N_NODES) - mu * mu;
  float sc = rsqrtf(var + EPS) * gamma[lane];
  float sh = beta[lane] - mu * sc;
  float sum = 0.f, mx = 0.f;
  for (int r = s0 + wid; r < s1; r += 4) {
    float v = bf16_to_f32(h1b[r * 64 + lane]) * sc + sh;
    v = v > 0.f ? v : 0.f;
    sum += v;
    mx = v > mx ? v : mx;
  }
  ssum[wid][lane] = sum;
  smax[wid][lane] = mx;
  __syncthreads();
  if (wid == 0) {
    float s = ssum[0][lane] + ssum[1][lane] + ssum[2][lane] + ssum[3][lane];
    float m = fmaxf(fmaxf(smax[0][lane], smax[1][lane]), fmaxf(smax[2][lane], smax[3][lane]));
    int cnt = s1 - s0;
    float inv = 1.0f / (float)(cnt > 0 ? cnt : 1);
    hgraph[g * 128 + lane] = s * inv;
    hgraph[g * 128 + 64 + lane] = m;
  }
}

__global__ void k_head(const float* __restrict__ hgraph,
                       const float* __restrict__ emb, const int* __restrict__ recipe,
                       const float* __restrict__ conv_w, const float* __restrict__ conv_b,
                       const float* __restrict__ fc_w, const float* __restrict__ fc_b,
                       const float* __restrict__ m1_w, const float* __restrict__ m1_b,
                       const float* __restrict__ m2_w, const float* __restrict__ m2_b,
                       const float* __restrict__ m3_w, const float* __restrict__ m3_b,
                       float* __restrict__ out) {
  __shared__ float r_s[RLEN][EMBED];
  __shared__ float convout[16 * RLEN];
  __shared__ float cvec[192];
  __shared__ float y1[128];
  __shared__ float y2[64];
  __shared__ int rec_s[RLEN];
  __shared__ float emb_s[80];
  int g = blockIdx.x;
  int t = threadIdx.x;
  if (t < 80) emb_s[t] = emb[t];
  if (t < RLEN) rec_s[t] = recipe[g * RLEN + t];
  __syncthreads();
  for (int idx = t; idx < RLEN * EMBED; idx += blockDim.x) {
    int pos = idx >> 3, e = idx & 7;
    r_s[pos][e] = emb_s[rec_s[pos] * EMBED + e];
  }
  if (t < 128) cvec[t] = hgraph[g * 128 + t];
  __syncthreads();
  for (int idx = t; idx < 16 * RLEN; idx += blockDim.x) {
    int c = idx / RLEN, pos = idx % RLEN;
    float acc = conv_b[c];
    #pragma unroll
    for (int k = 0; k < 3; ++k) {
      int p = pos + k - 1;
      if (p >= 0 && p < RLEN) {
        #pragma unroll
        for (int e = 0; e < EMBED; ++e)
          acc = fmaf(r_s[p][e], conv_w[(c * EMBED + e) * 3 + k], acc);
      }
    }
    convout[c * RLEN + pos] = acc > 0.f ? acc : 0.f;
  }
  __syncthreads();
  if (t < 64) {
    float acc = fc_b[t];
    for (int i = 0; i < 320; ++i) acc = fmaf(convout[i], fc_w[i * 64 + t], acc);
    cvec[128 + t] = acc > 0.f ? acc : 0.f;
  }
  __syncthreads();
  if (t < 128) {
    float acc = m1_b[t];
    for (int i = 0; i < 192; ++i) acc = fmaf(cvec[i], m1_w[i * 128 + t], acc);
    y1[t] = acc > 0.f ? acc : 0.f;
  }
  __syncthreads();
  if (t < 64) {
    float acc = m2_b[t];
    for (int i = 0; i < 128; ++i) acc = fmaf(y1[i], m2_w[i * 64 + t], acc);
    y2[t] = acc > 0.f ? acc : 0.f;
  }
  __syncthreads();
  if (t < 3) {
    float acc = m3_b[t];
    for (int i = 0; i < 64; ++i) acc = fmaf(y2[i], m3_w[i * 3 + t], acc);
    out[g * 3 + t] = acc;
  }
}

extern "C" void kernel_launch(void* const* d_in, const int* in_sizes, int n_in,
                              void* d_out, int out_size, void* d_ws, size_t ws_size,
                              hipStream_t stream) {
  const float* x      = (const float*)d_in[0];
  const float* W1     = (const float*)d_in[1];
  // b1 (d_in[2]) cancels under BN
  const float* gamma1 = (const float*)d_in[3];
  const float* beta1  = (const float*)d_in[4];
  const float* W2     = (const float*)d_in[5];
  // b2 (d_in[6]) cancels under BN
  const float* gamma2 = (const float*)d_in[7];
  const float* beta2  = (const float*)d_in[8];
  const float* emb    = (const float*)d_in[9];
  const float* conv_w = (const float*)d_in[10];
  const float* conv_b = (const float*)d_in[11];
  const float* fc_w   = (const float*)d_in[12];
  const float* fc_b   = (const float*)d_in[13];
  const float* m1_w   = (const float*)d_in[14];
  const float* m1_b   = (const float*)d_in[15];
  const float* m2_w   = (const float*)d_in[16];
  const float* m2_b   = (const float*)d_in[17];
  const float* m3_w   = (const float*)d_in[18];
  const float* m3_b   = (const float*)d_in[19];
  const int* ei       = (const int*)d_in[20];
  const int* batch    = (const int*)d_in[21];
  const int* recipe   = (const int*)d_in[22];
  const int* e_src = ei;
  const int* e_dst = ei + N_EDGES;
  float* out = (float*)d_out;

  char* p = (char*)d_ws;
  auto alloc = [&](size_t bytes) {
    char* r = p;
    p += (bytes + 255) & ~(size_t)255;
    return (void*)r;
  };
  int*   bcursor  = (int*)alloc((size_t)NBKT * 4);
  float* dinv     = (float*)alloc((size_t)N_NODES * 4);
  int*   rowstart = (int*)alloc((size_t)N_NODES * 4);
  int*   rowlen   = (int*)alloc((size_t)N_NODES * 4);
  float* stats    = (float*)alloc(256 * 4);
  float* mom      = (float*)alloc(16 * 4);
  float* hgraph   = (float*)alloc((size_t)N_GRAPHS * 128 * 4);
  int*   cols     = (int*)alloc((size_t)NBKT * CAP * 4);
  float4* xs      = (float4*)alloc((size_t)N_NODES * 16);
  float4* tbuf    = (float4*)alloc((size_t)N_NODES * 16);
  int*   ebuf     = (int*)alloc((size_t)NBKT * CAP * 4);
  ushort_t* hb    = (ushort_t*)alloc((size_t)N_NODES * 64 * 2);
  ushort_t* h1b   = (ushort_t*)ebuf;  // alias: ebuf dead before k_agg2 writes h1b

  hipMemsetAsync(bcursor, 0, (size_t)NBKT * 4, stream);
  hipMemsetAsync(stats, 0, 256 * 4, stream);
  hipMemsetAsync(mom, 0, 16 * 4, stream);

  k_bscatter<<<(N_EDGES + CHUNK - 1) / CHUNK, 512, 0, stream>>>(e_src, e_dst, bcursor, ebuf);
  k_bfill<<<NBKT, 256, 0, stream>>>(bcursor, ebuf, x, rowstart, rowlen, dinv, xs, cols);
  k_agg1<<<(N_NODES + 255) / 256, 256, 0, stream>>>(xs, tbuf, rowstart, rowlen, cols, dinv, mom);
  k_l2m2<<<625, 256, 0, stream>>>(tbuf, hb, W1, W2, mom, gamma1, beta1, dinv);
  k_agg2<<<(N_NODES + 3) / 4, 256, 0, stream>>>(hb, h1b, rowstart, rowlen, cols, dinv);
  k_bnstats_b<<<512, 256, 0, stream>>>(h1b, stats);
  k_pool<<<N_GRAPHS, 256, 0, stream>>>(h1b, stats, gamma2, beta2, batch, hgraph);
  k_head<<<N_GRAPHS, 128, 0, stream>>>(hgraph, emb, recipe, conv_w, conv_b, fc_w, fc_b,
                                       m1_w, m1_b, m2_w, m2_b, m3_w, m3_b, out);
}

// Round 12
// 409.691 us; speedup vs baseline: 1.0880x; 1.0099x over previous
//
#include <hip/hip_runtime.h>

#define N_NODES 200000
#define N_EDGES 6400000
#define N_GRAPHS 512
#define RLEN 20
#define EMBED 8
#define EPS 1e-5f

#define NPB 1024                           // nodes per bucket
#define NBKT ((N_NODES + NPB - 1) / NPB)   // 196
#define CHUNK 8192                         // edges per k_bscatter block (512 thr x 16)
#define CAP 36864                          // padded bucket capacity (mean 32653 + 23 sigma)

typedef unsigned short ushort_t;
typedef __attribute__((ext_vector_type(8))) short short8;
typedef __attribute__((ext_vector_type(4))) float f32x4;

__device__ inline ushort_t f32_to_bf16(float f) {
  unsigned u = __float_as_uint(f);
  unsigned r = (u + 0x7fff + ((u >> 16) & 1)) >> 16;  // RNE
  return (ushort_t)r;
}
__device__ inline float bf16_to_f32(ushort_t us) {
  return __uint_as_float(((unsigned)us) << 16);
}
__device__ inline float bfu_lo(unsigned u) { return __uint_as_float(u << 16); }
__device__ inline float bfu_hi(unsigned u) { return __uint_as_float(u & 0xFFFF0000u); }

// ---------------- bucketed CSR build (padded buckets; direct-write scatter) ----------------
// bcursor[b] holds COUNT (memset 0); ebuf slot = b*CAP + rank.
// Per-wave histograms cut LDS atomic contention 8x.

__global__ void __launch_bounds__(512) k_bscatter(const int* __restrict__ src,
                                                  const int* __restrict__ dst,
                                                  int* __restrict__ bcursor,
                                                  int* __restrict__ ebuf) {
  __shared__ int hist[8][256];
  __shared__ int gbase[256];
  int t = threadIdx.x;
  int wid = t >> 6;
  for (int i = t; i < 8 * 256; i += 512) ((int*)hist)[i] = 0;
  __syncthreads();

  const int4* src4 = (const int4*)(src + blockIdx.x * CHUNK);
  const int4* dst4 = (const int4*)(dst + blockIdx.x * CHUNK);
  int e0 = blockIdx.x * CHUNK;
  int nrem = N_EDGES - e0;
  int nv = (nrem >= CHUNK ? CHUNK : nrem) >> 2;     // int4 groups (N_EDGES%4==0)

  int pk[16], bk[16], rk[16];
  #pragma unroll
  for (int g = 0; g < 4; ++g) {
    int vi = g * 512 + t;
    if (vi < nv) {
      int4 s4 = src4[vi];
      int4 d4 = dst4[vi];
      #pragma unroll
      for (int c = 0; c < 4; ++c) {
        int s = (&s4.x)[c], d = (&d4.x)[c];
        int b = d >> 10;
        pk[g * 4 + c] = s | ((d & (NPB - 1)) << 18);
        bk[g * 4 + c] = b;
        rk[g * 4 + c] = atomicAdd(&hist[wid][b], 1);
      }
    } else {
      #pragma unroll
      for (int c = 0; c < 4; ++c) bk[g * 4 + c] = -1;
    }
  }
  __syncthreads();
  if (t < 256) {
    int s = 0;
    #pragma unroll
    for (int w = 0; w < 8; ++w) { int v = hist[w][t]; hist[w][t] = s; s += v; }
    if (t < NBKT && s > 0) gbase[t] = t * CAP + atomicAdd(&bcursor[t], s);
  }
  __syncthreads();
  #pragma unroll
  for (int k = 0; k < 16; ++k) {
    if (bk[k] >= 0) ebuf[gbase[bk[k]] + hist[wid][bk[k]] + rk[k]] = pk[k];
  }
}

// per bucket: degrees -> rowstart/rowlen/dinv/xs, then local scatter of cols.
// 1024 threads (16 waves) for latency hiding; grid = 196 blocks (<=1 block/CU).
__global__ void __launch_bounds__(1024) k_bfill(const int* __restrict__ bcursor,
                                                const int* __restrict__ ebuf,
                                                const float* __restrict__ x,
                                                int* __restrict__ rowstart,
                                                int* __restrict__ rowlen,
                                                float* __restrict__ dinv,
                                                float4* __restrict__ xs,
                                                int* __restrict__ cols) {
  __shared__ int deg[NPB];
  __shared__ int cur[NPB];
  __shared__ int wsum[16];
  int b = blockIdx.x;
  int t = threadIdx.x;               // 0..1023
  int lane = t & 63, wid = t >> 6;   // 16 waves
  int estart = b * CAP;
  int cnt = bcursor[b];
  int eend = estart + cnt;
  int nv = cnt >> 2;
  const int4* eb4 = (const int4*)(ebuf + estart);   // estart % 4 == 0
  deg[t] = 0;
  __syncthreads();
  for (int i = t; i < nv; i += 1024) {
    int4 p4 = eb4[i];
    atomicAdd(&deg[((unsigned)p4.x) >> 18], 1);
    atomicAdd(&deg[((unsigned)p4.y) >> 18], 1);
    atomicAdd(&deg[((unsigned)p4.z) >> 18], 1);
    atomicAdd(&deg[((unsigned)p4.w) >> 18], 1);
  }
  for (int i = estart + (nv << 2) + t; i < eend; i += 1024) {
    int p = ebuf[i];
    atomicAdd(&deg[((unsigned)p) >> 18], 1);
  }
  __syncthreads();
  // block exclusive scan, one element per thread
  int v = deg[t];
  int incl = v;
  #pragma unroll
  for (int off = 1; off < 64; off <<= 1) {
    int u = __shfl_up(incl, off);
    if (lane >= off) incl += u;
  }
  if (lane == 63) wsum[wid] = incl;
  __syncthreads();
  int wbase = 0;
  for (int w = 0; w < wid; ++w) wbase += wsum[w];
  int excl = wbase + incl - v;
  cur[t] = excl;
  int n = b * NPB + t;
  if (n < N_NODES) {
    rowstart[n] = estart + excl;
    rowlen[n] = v;
    float dv = rsqrtf((float)(v + 1));
    dinv[n] = dv;
    float4 o;
    o.x = x[n * 3 + 0] * dv;
    o.y = x[n * 3 + 1] * dv;
    o.z = x[n * 3 + 2] * dv;
    o.w = 0.f;
    xs[n] = o;
  }
  __syncthreads();
  for (int i = t; i < nv; i += 1024) {
    int4 p4 = eb4[i];
    #pragma unroll
    for (int c = 0; c < 4; ++c) {
      int p = (&p4.x)[c];
      int dl = ((unsigned)p) >> 18;
      int lpos = atomicAdd(&cur[dl], 1);
      cols[estart + lpos] = p & 0x3FFFF;
    }
  }
  for (int i = estart + (nv << 2) + t; i < eend; i += 1024) {
    int p = ebuf[i];
    int dl = ((unsigned)p) >> 18;
    int lpos = atomicAdd(&cur[dl], 1);
    cols[estart + lpos] = p & 0x3FFFF;
  }
}

// ---------------- layer-1: aggregate 3-feature x + fused 3x3 moments ----------------

__global__ void k_agg1(const float4* __restrict__ xs, float4* __restrict__ t,
                       const int* __restrict__ rowstart, const int* __restrict__ rowlen,
                       const int* __restrict__ cols,
                       const float* __restrict__ dinv, float* __restrict__ mom) {
  int n = blockIdx.x * blockDim.x + threadIdx.x;
  float m9[9] = {0.f, 0.f, 0.f, 0.f, 0.f, 0.f, 0.f, 0.f, 0.f};
  if (n < N_NODES) {
    float4 self = xs[n];
    float a0 = self.x, a1 = self.y, a2 = self.z;
    float b0 = 0.f, b1 = 0.f, b2 = 0.f;
    float c0 = 0.f, c1 = 0.f, c2 = 0.f;
    float e0 = 0.f, e1 = 0.f, e2 = 0.f;
    int base = rowstart[n];
    int len = rowlen[n];
    int j = 0;
    for (; j + 8 <= len; j += 8) {   // 8 float4 loads in flight
      int s0 = cols[base + j],     s1 = cols[base + j + 1];
      int s2 = cols[base + j + 2], s3 = cols[base + j + 3];
      int s4 = cols[base + j + 4], s5 = cols[base + j + 5];
      int s6 = cols[base + j + 6], s7 = cols[base + j + 7];
      float4 v0 = xs[s0], v1 = xs[s1], v2 = xs[s2], v3 = xs[s3];
      float4 v4 = xs[s4], v5 = xs[s5], v6 = xs[s6], v7 = xs[s7];
      a0 += v0.x + v4.x; a1 += v0.y + v4.y; a2 += v0.z + v4.z;
      b0 += v1.x + v5.x; b1 += v1.y + v5.y; b2 += v1.z + v5.z;
      c0 += v2.x + v6.x; c1 += v2.y + v6.y; c2 += v2.z + v6.z;
      e0 += v3.x + v7.x; e1 += v3.y + v7.y; e2 += v3.z + v7.z;
    }
    for (; j + 4 <= len; j += 4) {
      int s0 = cols[base + j], s1 = cols[base + j + 1];
      int s2 = cols[base + j + 2], s3 = cols[base + j + 3];
      float4 v0 = xs[s0], v1 = xs[s1], v2 = xs[s2], v3 = xs[s3];
      a0 += v0.x; a1 += v0.y; a2 += v0.z;
      b0 += v1.x; b1 += v1.y; b2 += v1.z;
      c0 += v2.x; c1 += v2.y; c2 += v2.z;
      e0 += v3.x; e1 += v3.y; e2 += v3.z;
    }
    for (; j < len; ++j) {
      float4 v = xs[cols[base + j]];
      a0 += v.x; a1 += v.y; a2 += v.z;
    }
    float dv = dinv[n];
    float4 o;
    o.x = dv * ((a0 + b0) + (c0 + e0));
    o.y = dv * ((a1 + b1) + (c1 + e1));
    o.z = dv * ((a2 + b2) + (c2 + e2));
    o.w = 0.f;
    t[n] = o;
    m9[0] = o.x; m9[1] = o.y; m9[2] = o.z;
    m9[3] = o.x * o.x; m9[4] = o.x * o.y; m9[5] = o.x * o.z;
    m9[6] = o.y * o.y; m9[7] = o.y * o.z; m9[8] = o.z * o.z;
  }
  #pragma unroll
  for (int off = 32; off; off >>= 1) {
    #pragma unroll
    for (int i = 0; i < 9; ++i) m9[i] += __shfl_xor(m9[i], off);
  }
  __shared__ float ls[4][9];
  int lane = threadIdx.x & 63, wid = threadIdx.x >> 6;
  if (lane == 0) {
    #pragma unroll
    for (int i = 0; i < 9; ++i) ls[wid][i] = m9[i];
  }
  __syncthreads();
  if (threadIdx.x < 9) {
    float s = ls[0][threadIdx.x] + ls[1][threadIdx.x] + ls[2][threadIdx.x] + ls[3][threadIdx.x];
    atomicAdd(&mom[threadIdx.x], s);
  }
}

// fused layer-2 front end: h1 = t @ W1 (in-register), BN1 (stats from moments),
// relu, @W2 via split-bf16 MFMA, scale by dinv -> hb (bf16 only)
__global__ void __launch_bounds__(256) k_l2m2(const float4* __restrict__ t,
                                              ushort_t* __restrict__ hb,
                                              const float* __restrict__ W1,
                                              const float* __restrict__ W2,
                                              const float* __restrict__ mom,
                                              const float* __restrict__ gamma,
                                              const float* __restrict__ beta,
                                              const float* __restrict__ dinv) {
  __shared__ float w1s[192];
  __shared__ ushort_t w2t_hi[64 * 64];   // [out_feat][k]
  __shared__ ushort_t w2t_lo[64 * 64];
  __shared__ float tt[4][16][4];
  __shared__ ushort_t at_hi[4][16 * 64];
  __shared__ ushort_t at_lo[4][16 * 64];
  int tix = threadIdx.x;
  int lane = tix & 63, wid = tix >> 6;
  if (tix < 192) w1s[tix] = W1[tix];
  for (int i = tix; i < 64 * 64; i += 256) {
    int f = i >> 6, k = i & 63;
    float w = W2[k * 64 + f];
    ushort_t hi = f32_to_bf16(w);
    w2t_hi[i] = hi;
    w2t_lo[i] = f32_to_bf16(w - bf16_to_f32(hi));
  }
  __syncthreads();

  int col = lane & 15, kb = lane >> 4;
  short8 bhi[4][2], blo[4][2];
  #pragma unroll
  for (int nt = 0; nt < 4; ++nt) {
    #pragma unroll
    for (int ks = 0; ks < 2; ++ks) {
      int base = (nt * 16 + col) * 64 + ks * 32 + kb * 8;
      bhi[nt][ks] = *reinterpret_cast<const short8*>(&w2t_hi[base]);
      blo[nt][ks] = *reinterpret_cast<const short8*>(&w2t_lo[base]);
    }
  }

  float inv_n = 1.0f / N_NODES;
  float w0 = w1s[lane], w1 = w1s[64 + lane], w2 = w1s[128 + lane];
  float mu = (mom[0] * w0 + mom[1] * w1 + mom[2] * w2) * inv_n;
  float eh2 = (mom[3] * w0 * w0 + 2.f * mom[4] * w0 * w1 + 2.f * mom[5] * w0 * w2 +
               mom[6] * w1 * w1 + 2.f * mom[7] * w1 * w2 + mom[8] * w2 * w2) * inv_n;
  float var = eh2 - mu * mu;
  float sc = rsqrtf(var + EPS) * gamma[lane];
  float sh = beta[lane] - mu * sc;

  for (int bt = blockIdx.x; bt < 3125; bt += gridDim.x) {
    int n0 = (bt * 4 + wid) * 16;
    if (lane < 16) {
      float4 v = t[n0 + lane];
      tt[wid][lane][0] = v.x; tt[wid][lane][1] = v.y; tt[wid][lane][2] = v.z;
    }
    #pragma unroll 4
    for (int i = 0; i < 16; ++i) {
      float h = tt[wid][i][0] * w0 + tt[wid][i][1] * w1 + tt[wid][i][2] * w2;
      float a = h * sc + sh;
      a = a > 0.f ? a : 0.f;
      ushort_t hi = f32_to_bf16(a);
      at_hi[wid][i * 64 + lane] = hi;
      at_lo[wid][i * 64 + lane] = f32_to_bf16(a - bf16_to_f32(hi));
    }
    short8 ahi[2], alo[2];
    #pragma unroll
    for (int ks = 0; ks < 2; ++ks) {
      int base = col * 64 + ks * 32 + kb * 8;   // A: row=lane&15, k-block
      ahi[ks] = *reinterpret_cast<const short8*>(&at_hi[wid][base]);
      alo[ks] = *reinterpret_cast<const short8*>(&at_lo[wid][base]);
    }
    float dv[4];
    #pragma unroll
    for (int r = 0; r < 4; ++r) dv[r] = dinv[n0 + kb * 4 + r];

    #pragma unroll
    for (int nt = 0; nt < 4; ++nt) {
      f32x4 acc = {0.f, 0.f, 0.f, 0.f};
      #pragma unroll
      for (int ks = 0; ks < 2; ++ks) {
        acc = __builtin_amdgcn_mfma_f32_16x16x32_bf16(ahi[ks], bhi[nt][ks], acc, 0, 0, 0);
        acc = __builtin_amdgcn_mfma_f32_16x16x32_bf16(ahi[ks], blo[nt][ks], acc, 0, 0, 0);
        acc = __builtin_amdgcn_mfma_f32_16x16x32_bf16(alo[ks], bhi[nt][ks], acc, 0, 0, 0);
      }
      #pragma unroll
      for (int r = 0; r < 4; ++r) {
        int node = n0 + kb * 4 + r;      // C/D: row=(lane>>4)*4+r, col=lane&15
        int feat = nt * 16 + col;
        hb[node * 64 + feat] = f32_to_bf16(acc[r] * dv[r]);
      }
    }
  }
}

// layer-2 aggregation (round-8 proven shape): one node per wave, dword gather,
// 8-neighbor groups (4 loads in flight per lane). Writes packed bf16 h1.
__global__ void k_agg2(const ushort_t* __restrict__ hb, ushort_t* __restrict__ h1b,
                       const int* __restrict__ rowstart, const int* __restrict__ rowlen,
                       const int* __restrict__ cols, const float* __restrict__ dinv) {
  int node = blockIdx.x * 4 + (threadIdx.x >> 6);
  int lane = threadIdx.x & 63;
  if (node >= N_NODES) return;
  int half = lane >> 5;
  int fl = lane & 31;
  const unsigned* hb32 = (const unsigned*)hb;      // hb32[s*32+fl] = feats {2fl, 2fl+1}
  unsigned* o32 = (unsigned*)h1b;
  float2 acc;
  if (half == 0) {                                  // self loop (bf16)
    unsigned u = hb32[node * 32 + fl];
    acc.x = bfu_lo(u); acc.y = bfu_hi(u);
  } else { acc.x = 0.f; acc.y = 0.f; }
  int base = rowstart[node];
  int len = rowlen[node];
  for (int c0 = 0; c0 < len; c0 += 64) {
    int rem = len - c0;
    int m = rem < 64 ? rem : 64;
    int cidx = (lane < m) ? cols[base + c0 + lane] : 0;
    int j = 0;
    for (; j + 8 <= m; j += 8) {   // 8 neighbors / iter, 4 dword loads in flight per lane
      int sA = __shfl(cidx, j + half);
      int sB = __shfl(cidx, j + 2 + half);
      int sC = __shfl(cidx, j + 4 + half);
      int sD = __shfl(cidx, j + 6 + half);
      unsigned uA = hb32[sA * 32 + fl], uB = hb32[sB * 32 + fl];
      unsigned uC = hb32[sC * 32 + fl], uD = hb32[sD * 32 + fl];
      acc.x += (bfu_lo(uA) + bfu_lo(uB)) + (bfu_lo(uC) + bfu_lo(uD));
      acc.y += (bfu_hi(uA) + bfu_hi(uB)) + (bfu_hi(uC) + bfu_hi(uD));
    }
    for (; j + 2 <= m; j += 2) {
      int s = __shfl(cidx, j + half);
      unsigned u = hb32[s * 32 + fl];
      acc.x += bfu_lo(u);
      acc.y += bfu_hi(u);
    }
    if (j < m) {                   // odd leftover: half0 only
      int s = __shfl(cidx, j);
      if (half == 0) {
        unsigned u = hb32[s * 32 + fl];
        acc.x += bfu_lo(u);
        acc.y += bfu_hi(u);
      }
    }
  }
  acc.x += __shfl_xor(acc.x, 32);
  acc.y += __shfl_xor(acc.y, 32);
  if (half == 0) {
    float dv = dinv[node];
    float ox = acc.x * dv, oy = acc.y * dv;
    o32[node * 32 + fl] = ((unsigned)f32_to_bf16(oy) << 16) | (unsigned)f32_to_bf16(ox);
  }
}

// BN2 stats from packed bf16 h1 -> stats[0:64], stats[64:128]
__global__ void k_bnstats_b(const ushort_t* __restrict__ h1b, float* __restrict__ stats) {
  const unsigned* h32 = (const unsigned*)h1b;
  int tid = threadIdx.x;
  int lane = tid & 63, wid = tid >> 6;
  int fl = lane & 31, rsel = lane >> 5;
  float s0 = 0.f, s1 = 0.f, q0 = 0.f, q1 = 0.f;
  for (int r = blockIdx.x * 8 + wid * 2 + rsel; r < N_NODES; r += gridDim.x * 8) {
    unsigned u = h32[r * 32 + fl];
    float a = bfu_lo(u), b = bfu_hi(u);
    s0 += a; s1 += b; q0 += a * a; q1 += b * b;
  }
  s0 += __shfl_xor(s0, 32); s1 += __shfl_xor(s1, 32);
  q0 += __shfl_xor(q0, 32); q1 += __shfl_xor(q1, 32);
  __shared__ float ls[4][64], lq[4][64];
  if (rsel == 0) {
    ls[wid][2 * fl] = s0; ls[wid][2 * fl + 1] = s1;
    lq[wid][2 * fl] = q0; lq[wid][2 * fl + 1] = q1;
  }
  __syncthreads();
  if (tid < 64) {
    float a = ls[0][tid] + ls[1][tid] + ls[2][tid] + ls[3][tid];
    float b = lq[0][tid] + lq[1][tid] + lq[2][tid] + lq[3][tid];
    atomicAdd(&stats[tid], a);
    atomicAdd(&stats[64 + tid], b);
  }
}

// ---------------- pooling + head ----------------

// pool with fused per-graph range search (batch is sorted)
__global__ void k_pool(const ushort_t* __restrict__ h1b, const float* __restrict__ stats2,
                       const float* __restrict__ gamma, const float* __restrict__ beta,
                       const int* __restrict__ batch, float* __restrict__ hgraph) {
  __shared__ float ssum[4][64], smax[4][64];
  __shared__ int sb[2];
  int g = blockIdx.x;
  int lane = threadIdx.x & 63, wid = threadIdx.x >> 6;
  if (threadIdx.x < 2) {
    int tg = g + threadIdx.x;
    int lo = 0, hi = N_NODES;
    while (lo < hi) {
      int mid = (lo + hi) >> 1;
      if (batch[mid] < tg) lo = mid + 1; else hi = mid;
    }
    sb[threadIdx.x] = lo;
  }
  __syncthreads();
  int s0 = sb[0], s1 = sb[1];
  float mu = stats2[lane] * (1.0f / N_NODES);
  float var = stats2[64 + lane] * (1.0f / N_NODES) - mu * mu;
  float sc = rsqrtf(var + EPS) * gamma[lane];
  float sh = beta[lane] - mu * sc;
  float sum = 0.f, mx = 0.f;
  for (int r = s0 + wid; r < s1; r += 4) {
    float v = bf16_to_f32(h1b[r * 64 + lane]) * sc + sh;
    v = v > 0.f ? v : 0.f;
    sum += v;
    mx = v > mx ? v : mx;
  }
  ssum[wid][lane] = sum;
  smax[wid][lane] = mx;
  __syncthreads();
  if (wid == 0) {
    float s = ssum[0][lane] + ssum[1][lane] + ssum[2][lane] + ssum[3][lane];
    float m = fmaxf(fmaxf(smax[0][lane], smax[1][lane]), fmaxf(smax[2][lane], smax[3][lane]));
    int cnt = s1 - s0;
    float inv = 1.0f / (float)(cnt > 0 ? cnt : 1);
    hgraph[g * 128 + lane] = s * inv;
    hgraph[g * 128 + 64 + lane] = m;
  }
}

__global__ void k_head(const float* __restrict__ hgraph,
                       const float* __restrict__ emb, const int* __restrict__ recipe,
                       const float* __restrict__ conv_w, const float* __restrict__ conv_b,
                       const float* __restrict__ fc_w, const float* __restrict__ fc_b,
                       const float* __restrict__ m1_w, const float* __restrict__ m1_b,
                       const float* __restrict__ m2_w, const float* __restrict__ m2_b,
                       const float* __restrict__ m3_w, const float* __restrict__ m3_b,
                       float* __restrict__ out) {
  __shared__ float r_s[RLEN][EMBED];
  __shared__ float convout[16 * RLEN];
  __shared__ float cvec[192];
  __shared__ float y1[128];
  __shared__ float y2[64];
  __shared__ int rec_s[RLEN];
  __shared__ float emb_s[80];
  int g = blockIdx.x;
  int t = threadIdx.x;
  if (t < 80) emb_s[t] = emb[t];
  if (t < RLEN) rec_s[t] = recipe[g * RLEN + t];
  __syncthreads();
  for (int idx = t; idx < RLEN * EMBED; idx += blockDim.x) {
    int pos = idx >> 3, e = idx & 7;
    r_s[pos][e] = emb_s[rec_s[pos] * EMBED + e];
  }
  if (t < 128) cvec[t] = hgraph[g * 128 + t];
  __syncthreads();
  for (int idx = t; idx < 16 * RLEN; idx += blockDim.x) {
    int c = idx / RLEN, pos = idx % RLEN;
    float acc = conv_b[c];
    #pragma unroll
    for (int k = 0; k < 3; ++k) {
      int p = pos + k - 1;
      if (p >= 0 && p < RLEN) {
        #pragma unroll
        for (int e = 0; e < EMBED; ++e)
          acc = fmaf(r_s[p][e], conv_w[(c * EMBED + e) * 3 + k], acc);
      }
    }
    convout[c * RLEN + pos] = acc > 0.f ? acc : 0.f;
  }
  __syncthreads();
  if (t < 64) {
    float acc = fc_b[t];
    for (int i = 0; i < 320; ++i) acc = fmaf(convout[i], fc_w[i * 64 + t], acc);
    cvec[128 + t] = acc > 0.f ? acc : 0.f;
  }
  __syncthreads();
  if (t < 128) {
    float acc = m1_b[t];
    for (int i = 0; i < 192; ++i) acc = fmaf(cvec[i], m1_w[i * 128 + t], acc);
    y1[t] = acc > 0.f ? acc : 0.f;
  }
  __syncthreads();
  if (t < 64) {
    float acc = m2_b[t];
    for (int i = 0; i < 128; ++i) acc = fmaf(y1[i], m2_w[i * 64 + t], acc);
    y2[t] = acc > 0.f ? acc : 0.f;
  }
  __syncthreads();
  if (t < 3) {
    float acc = m3_b[t];
    for (int i = 0; i < 64; ++i) acc = fmaf(y2[i], m3_w[i * 3 + t], acc);
    out[g * 3 + t] = acc;
  }
}

extern "C" void kernel_launch(void* const* d_in, const int* in_sizes, int n_in,
                              void* d_out, int out_size, void* d_ws, size_t ws_size,
                              hipStream_t stream) {
  const float* x      = (const float*)d_in[0];
  const float* W1     = (const float*)d_in[1];
  // b1 (d_in[2]) cancels under BN
  const float* gamma1 = (const float*)d_in[3];
  const float* beta1  = (const float*)d_in[4];
  const float* W2     = (const float*)d_in[5];
  // b2 (d_in[6]) cancels under BN
  const float* gamma2 = (const float*)d_in[7];
  const float* beta2  = (const float*)d_in[8];
  const float* emb    = (const float*)d_in[9];
  const float* conv_w = (const float*)d_in[10];
  const float* conv_b = (const float*)d_in[11];
  const float* fc_w   = (const float*)d_in[12];
  const float* fc_b   = (const float*)d_in[13];
  const float* m1_w   = (const float*)d_in[14];
  const float* m1_b   = (const float*)d_in[15];
  const float* m2_w   = (const float*)d_in[16];
  const float* m2_b   = (const float*)d_in[17];
  const float* m3_w   = (const float*)d_in[18];
  const float* m3_b   = (const float*)d_in[19];
  const int* ei       = (const int*)d_in[20];
  const int* batch    = (const int*)d_in[21];
  const int* recipe   = (const int*)d_in[22];
  const int* e_src = ei;
  const int* e_dst = ei + N_EDGES;
  float* out = (float*)d_out;

  char* p = (char*)d_ws;
  auto alloc = [&](size_t bytes) {
    char* r = p;
    p += (bytes + 255) & ~(size_t)255;
    return (void*)r;
  };
  int*   bcursor  = (int*)alloc((size_t)NBKT * 4);
  float* dinv     = (float*)alloc((size_t)N_NODES * 4);
  int*   rowstart = (int*)alloc((size_t)N_NODES * 4);
  int*   rowlen   = (int*)alloc((size_t)N_NODES * 4);
  float* stats    = (float*)alloc(256 * 4);
  float* mom      = (float*)alloc(16 * 4);
  float* hgraph   = (float*)alloc((size_t)N_GRAPHS * 128 * 4);
  int*   cols     = (int*)alloc((size_t)NBKT * CAP * 4);
  float4* xs      = (float4*)alloc((size_t)N_NODES * 16);
  float4* tbuf    = (float4*)alloc((size_t)N_NODES * 16);
  int*   ebuf     = (int*)alloc((size_t)NBKT * CAP * 4);
  ushort_t* hb    = (ushort_t*)alloc((size_t)N_NODES * 64 * 2);
  ushort_t* h1b   = (ushort_t*)ebuf;  // alias: ebuf dead before k_agg2 writes h1b

  hipMemsetAsync(bcursor, 0, (size_t)NBKT * 4, stream);
  hipMemsetAsync(stats, 0, 256 * 4, stream);
  hipMemsetAsync(mom, 0, 16 * 4, stream);

  k_bscatter<<<(N_EDGES + CHUNK - 1) / CHUNK, 512, 0, stream>>>(e_src, e_dst, bcursor, ebuf);
  k_bfill<<<NBKT, 1024, 0, stream>>>(bcursor, ebuf, x, rowstart, rowlen, dinv, xs, cols);
  k_agg1<<<(N_NODES + 255) / 256, 256, 0, stream>>>(xs, tbuf, rowstart, rowlen, cols, dinv, mom);
  k_l2m2<<<625, 256, 0, stream>>>(tbuf, hb, W1, W2, mom, gamma1, beta1, dinv);
  k_agg2<<<(N_NODES + 3) / 4, 256, 0, stream>>>(hb, h1b, rowstart, rowlen, cols, dinv);
  k_bnstats_b<<<512, 256, 0, stream>>>(h1b, stats);
  k_pool<<<N_GRAPHS, 256, 0, stream>>>(h1b, stats, gamma2, beta2, batch, hgraph);
  k_head<<<N_GRAPHS, 128, 0, stream>>>(hgraph, emb, recipe, conv_w, conv_b, fc_w, fc_b,
                                       m1_w, m1_b, m2_w, m2_b, m3_w, m3_b, out);
}

// Round 14
// 397.629 us; speedup vs baseline: 1.1211x; 1.0303x over previous
//
#include <hip/hip_runtime.h>

#define N_NODES 200000
#define N_EDGES 6400000
#define N_GRAPHS 512
#define RLEN 20
#define EMBED 8
#define EPS 1e-5f

#define NPB 1024                           // nodes per bucket
#define NBKT ((N_NODES + NPB - 1) / NPB)   // 196
#define CHUNK 8192                         // edges per k_bscatter block (512 thr x 16)
#define CAP 36864                          // padded bucket capacity (mean 32653 + 23 sigma)

typedef unsigned short ushort_t;
typedef __attribute__((ext_vector_type(8))) short short8;
typedef __attribute__((ext_vector_type(4))) float f32x4;

__device__ inline ushort_t f32_to_bf16(float f) {
  unsigned u = __float_as_uint(f);
  unsigned r = (u + 0x7fff + ((u >> 16) & 1)) >> 16;  // RNE
  return (ushort_t)r;
}
__device__ inline float bf16_to_f32(ushort_t us) {
  return __uint_as_float(((unsigned)us) << 16);
}
__device__ inline float bfu_lo(unsigned u) { return __uint_as_float(u << 16); }
__device__ inline float bfu_hi(unsigned u) { return __uint_as_float(u & 0xFFFF0000u); }

// ---------------- bucketed CSR build (padded buckets; direct-write scatter) ----------------
// bcursor[b] holds COUNT (memset 0); ebuf slot = b*CAP + rank.

__global__ void __launch_bounds__(512) k_bscatter(const int* __restrict__ src,
                                                  const int* __restrict__ dst,
                                                  int* __restrict__ bcursor,
                                                  int* __restrict__ ebuf) {
  __shared__ int hist[8][256];
  __shared__ int gbase[256];
  int t = threadIdx.x;
  int wid = t >> 6;
  for (int i = t; i < 8 * 256; i += 512) ((int*)hist)[i] = 0;
  __syncthreads();

  const int4* src4 = (const int4*)(src + blockIdx.x * CHUNK);
  const int4* dst4 = (const int4*)(dst + blockIdx.x * CHUNK);
  int e0 = blockIdx.x * CHUNK;
  int nrem = N_EDGES - e0;
  int nv = (nrem >= CHUNK ? CHUNK : nrem) >> 2;     // int4 groups (N_EDGES%4==0)

  int pk[16], bk[16], rk[16];
  #pragma unroll
  for (int g = 0; g < 4; ++g) {
    int vi = g * 512 + t;
    if (vi < nv) {
      int4 s4 = src4[vi];
      int4 d4 = dst4[vi];
      #pragma unroll
      for (int c = 0; c < 4; ++c) {
        int s = (&s4.x)[c], d = (&d4.x)[c];
        int b = d >> 10;
        pk[g * 4 + c] = s | ((d & (NPB - 1)) << 18);
        bk[g * 4 + c] = b;
        rk[g * 4 + c] = atomicAdd(&hist[wid][b], 1);
      }
    } else {
      #pragma unroll
      for (int c = 0; c < 4; ++c) bk[g * 4 + c] = -1;
    }
  }
  __syncthreads();
  if (t < 256) {
    int s = 0;
    #pragma unroll
    for (int w = 0; w < 8; ++w) { int v = hist[w][t]; hist[w][t] = s; s += v; }
    if (t < NBKT && s > 0) gbase[t] = t * CAP + atomicAdd(&bcursor[t], s);
  }
  __syncthreads();
  #pragma unroll
  for (int k = 0; k < 16; ++k) {
    if (bk[k] >= 0) ebuf[gbase[bk[k]] + hist[wid][bk[k]] + rk[k]] = pk[k];
  }
}

// per bucket: degrees -> rowstart/rowlen/dinv/xs, then local scatter of cols.
__global__ void __launch_bounds__(1024) k_bfill(const int* __restrict__ bcursor,
                                                const int* __restrict__ ebuf,
                                                const float* __restrict__ x,
                                                int* __restrict__ rowstart,
                                                int* __restrict__ rowlen,
                                                float* __restrict__ dinv,
                                                float4* __restrict__ xs,
                                                int* __restrict__ cols) {
  __shared__ int deg[NPB];
  __shared__ int cur[NPB];
  __shared__ int wsum[16];
  int b = blockIdx.x;
  int t = threadIdx.x;               // 0..1023
  int lane = t & 63, wid = t >> 6;   // 16 waves
  int estart = b * CAP;
  int cnt = bcursor[b];
  int eend = estart + cnt;
  int nv = cnt >> 2;
  const int4* eb4 = (const int4*)(ebuf + estart);   // estart % 4 == 0
  deg[t] = 0;
  __syncthreads();
  for (int i = t; i < nv; i += 1024) {
    int4 p4 = eb4[i];
    atomicAdd(&deg[((unsigned)p4.x) >> 18], 1);
    atomicAdd(&deg[((unsigned)p4.y) >> 18], 1);
    atomicAdd(&deg[((unsigned)p4.z) >> 18], 1);
    atomicAdd(&deg[((unsigned)p4.w) >> 18], 1);
  }
  for (int i = estart + (nv << 2) + t; i < eend; i += 1024) {
    int p = ebuf[i];
    atomicAdd(&deg[((unsigned)p) >> 18], 1);
  }
  __syncthreads();
  int v = deg[t];
  int incl = v;
  #pragma unroll
  for (int off = 1; off < 64; off <<= 1) {
    int u = __shfl_up(incl, off);
    if (lane >= off) incl += u;
  }
  if (lane == 63) wsum[wid] = incl;
  __syncthreads();
  int wbase = 0;
  for (int w = 0; w < wid; ++w) wbase += wsum[w];
  int excl = wbase + incl - v;
  cur[t] = excl;
  int n = b * NPB + t;
  if (n < N_NODES) {
    rowstart[n] = estart + excl;
    rowlen[n] = v;
    float dv = rsqrtf((float)(v + 1));
    dinv[n] = dv;
    float4 o;
    o.x = x[n * 3 + 0] * dv;
    o.y = x[n * 3 + 1] * dv;
    o.z = x[n * 3 + 2] * dv;
    o.w = 0.f;
    xs[n] = o;
  }
  __syncthreads();
  for (int i = t; i < nv; i += 1024) {
    int4 p4 = eb4[i];
    #pragma unroll
    for (int c = 0; c < 4; ++c) {
      int p = (&p4.x)[c];
      int dl = ((unsigned)p) >> 18;
      int lpos = atomicAdd(&cur[dl], 1);
      cols[estart + lpos] = p & 0x3FFFF;
    }
  }
  for (int i = estart + (nv << 2) + t; i < eend; i += 1024) {
    int p = ebuf[i];
    int dl = ((unsigned)p) >> 18;
    int lpos = atomicAdd(&cur[dl], 1);
    cols[estart + lpos] = p & 0x3FFFF;
  }
}

// ---------------- layer-1: aggregate 3-feature x + fused 3x3 moments ----------------

__global__ void k_agg1(const float4* __restrict__ xs, float4* __restrict__ t,
                       const int* __restrict__ rowstart, const int* __restrict__ rowlen,
                       const int* __restrict__ cols,
                       const float* __restrict__ dinv, float* __restrict__ mom) {
  int n = blockIdx.x * blockDim.x + threadIdx.x;
  float m9[9] = {0.f, 0.f, 0.f, 0.f, 0.f, 0.f, 0.f, 0.f, 0.f};
  if (n < N_NODES) {
    float4 self = xs[n];
    float a0 = self.x, a1 = self.y, a2 = self.z;
    float b0 = 0.f, b1 = 0.f, b2 = 0.f;
    float c0 = 0.f, c1 = 0.f, c2 = 0.f;
    float e0 = 0.f, e1 = 0.f, e2 = 0.f;
    int base = rowstart[n];
    int len = rowlen[n];
    int j = 0;
    for (; j + 8 <= len; j += 8) {   // 8 float4 loads in flight
      int s0 = cols[base + j],     s1 = cols[base + j + 1];
      int s2 = cols[base + j + 2], s3 = cols[base + j + 3];
      int s4 = cols[base + j + 4], s5 = cols[base + j + 5];
      int s6 = cols[base + j + 6], s7 = cols[base + j + 7];
      float4 v0 = xs[s0], v1 = xs[s1], v2 = xs[s2], v3 = xs[s3];
      float4 v4 = xs[s4], v5 = xs[s5], v6 = xs[s6], v7 = xs[s7];
      a0 += v0.x + v4.x; a1 += v0.y + v4.y; a2 += v0.z + v4.z;
      b0 += v1.x + v5.x; b1 += v1.y + v5.y; b2 += v1.z + v5.z;
      c0 += v2.x + v6.x; c1 += v2.y + v6.y; c2 += v2.z + v6.z;
      e0 += v3.x + v7.x; e1 += v3.y + v7.y; e2 += v3.z + v7.z;
    }
    for (; j + 4 <= len; j += 4) {
      int s0 = cols[base + j], s1 = cols[base + j + 1];
      int s2 = cols[base + j + 2], s3 = cols[base + j + 3];
      float4 v0 = xs[s0], v1 = xs[s1], v2 = xs[s2], v3 = xs[s3];
      a0 += v0.x; a1 += v0.y; a2 += v0.z;
      b0 += v1.x; b1 += v1.y; b2 += v1.z;
      c0 += v2.x; c1 += v2.y; c2 += v2.z;
      e0 += v3.x; e1 += v3.y; e2 += v3.z;
    }
    for (; j < len; ++j) {
      float4 v = xs[cols[base + j]];
      a0 += v.x; a1 += v.y; a2 += v.z;
    }
    float dv = dinv[n];
    float4 o;
    o.x = dv * ((a0 + b0) + (c0 + e0));
    o.y = dv * ((a1 + b1) + (c1 + e1));
    o.z = dv * ((a2 + b2) + (c2 + e2));
    o.w = 0.f;
    t[n] = o;
    m9[0] = o.x; m9[1] = o.y; m9[2] = o.z;
    m9[3] = o.x * o.x; m9[4] = o.x * o.y; m9[5] = o.x * o.z;
    m9[6] = o.y * o.y; m9[7] = o.y * o.z; m9[8] = o.z * o.z;
  }
  #pragma unroll
  for (int off = 32; off; off >>= 1) {
    #pragma unroll
    for (int i = 0; i < 9; ++i) m9[i] += __shfl_xor(m9[i], off);
  }
  __shared__ float ls[4][9];
  int lane = threadIdx.x & 63, wid = threadIdx.x >> 6;
  if (lane == 0) {
    #pragma unroll
    for (int i = 0; i < 9; ++i) ls[wid][i] = m9[i];
  }
  __syncthreads();
  if (threadIdx.x < 9) {
    float s = ls[0][threadIdx.x] + ls[1][threadIdx.x] + ls[2][threadIdx.x] + ls[3][threadIdx.x];
    atomicAdd(&mom[threadIdx.x], s);
  }
}

// fused layer-2 front end: h1 = t @ W1 (in-register), BN1 (stats from moments),
// relu, @W2 via split-bf16 MFMA, scale by dinv -> hb (bf16 only)
__global__ void __launch_bounds__(256) k_l2m2(const float4* __restrict__ t,
                                              ushort_t* __restrict__ hb,
                                              const float* __restrict__ W1,
                                              const float* __restrict__ W2,
                                              const float* __restrict__ mom,
                                              const float* __restrict__ gamma,
                                              const float* __restrict__ beta,
                                              const float* __restrict__ dinv) {
  __shared__ float w1s[192];
  __shared__ ushort_t w2t_hi[64 * 64];   // [out_feat][k]
  __shared__ ushort_t w2t_lo[64 * 64];
  __shared__ float tt[4][16][4];
  __shared__ ushort_t at_hi[4][16 * 64];
  __shared__ ushort_t at_lo[4][16 * 64];
  int tix = threadIdx.x;
  int lane = tix & 63, wid = tix >> 6;
  if (tix < 192) w1s[tix] = W1[tix];
  for (int i = tix; i < 64 * 64; i += 256) {
    int f = i >> 6, k = i & 63;
    float w = W2[k * 64 + f];
    ushort_t hi = f32_to_bf16(w);
    w2t_hi[i] = hi;
    w2t_lo[i] = f32_to_bf16(w - bf16_to_f32(hi));
  }
  __syncthreads();

  int col = lane & 15, kb = lane >> 4;
  short8 bhi[4][2], blo[4][2];
  #pragma unroll
  for (int nt = 0; nt < 4; ++nt) {
    #pragma unroll
    for (int ks = 0; ks < 2; ++ks) {
      int base = (nt * 16 + col) * 64 + ks * 32 + kb * 8;
      bhi[nt][ks] = *reinterpret_cast<const short8*>(&w2t_hi[base]);
      blo[nt][ks] = *reinterpret_cast<const short8*>(&w2t_lo[base]);
    }
  }

  float inv_n = 1.0f / N_NODES;
  float w0 = w1s[lane], w1 = w1s[64 + lane], w2 = w1s[128 + lane];
  float mu = (mom[0] * w0 + mom[1] * w1 + mom[2] * w2) * inv_n;
  float eh2 = (mom[3] * w0 * w0 + 2.f * mom[4] * w0 * w1 + 2.f * mom[5] * w0 * w2 +
               mom[6] * w1 * w1 + 2.f * mom[7] * w1 * w2 + mom[8] * w2 * w2) * inv_n;
  float var = eh2 - mu * mu;
  float sc = rsqrtf(var + EPS) * gamma[lane];
  float sh = beta[lane] - mu * sc;

  for (int bt = blockIdx.x; bt < 3125; bt += gridDim.x) {
    int n0 = (bt * 4 + wid) * 16;
    if (lane < 16) {
      float4 v = t[n0 + lane];
      tt[wid][lane][0] = v.x; tt[wid][lane][1] = v.y; tt[wid][lane][2] = v.z;
    }
    #pragma unroll 4
    for (int i = 0; i < 16; ++i) {
      float h = tt[wid][i][0] * w0 + tt[wid][i][1] * w1 + tt[wid][i][2] * w2;
      float a = h * sc + sh;
      a = a > 0.f ? a : 0.f;
      ushort_t hi = f32_to_bf16(a);
      at_hi[wid][i * 64 + lane] = hi;
      at_lo[wid][i * 64 + lane] = f32_to_bf16(a - bf16_to_f32(hi));
    }
    short8 ahi[2], alo[2];
    #pragma unroll
    for (int ks = 0; ks < 2; ++ks) {
      int base = col * 64 + ks * 32 + kb * 8;   // A: row=lane&15, k-block
      ahi[ks] = *reinterpret_cast<const short8*>(&at_hi[wid][base]);
      alo[ks] = *reinterpret_cast<const short8*>(&at_lo[wid][base]);
    }
    float dv[4];
    #pragma unroll
    for (int r = 0; r < 4; ++r) dv[r] = dinv[n0 + kb * 4 + r];

    #pragma unroll
    for (int nt = 0; nt < 4; ++nt) {
      f32x4 acc = {0.f, 0.f, 0.f, 0.f};
      #pragma unroll
      for (int ks = 0; ks < 2; ++ks) {
        acc = __builtin_amdgcn_mfma_f32_16x16x32_bf16(ahi[ks], bhi[nt][ks], acc, 0, 0, 0);
        acc = __builtin_amdgcn_mfma_f32_16x16x32_bf16(ahi[ks], blo[nt][ks], acc, 0, 0, 0);
        acc = __builtin_amdgcn_mfma_f32_16x16x32_bf16(alo[ks], bhi[nt][ks], acc, 0, 0, 0);
      }
      #pragma unroll
      for (int r = 0; r < 4; ++r) {
        int node = n0 + kb * 4 + r;      // C/D: row=(lane>>4)*4+r, col=lane&15
        int feat = nt * 16 + col;
        hb[node * 64 + feat] = f32_to_bf16(acc[r] * dv[r]);
      }
    }
  }
}

// layer-2 aggregation (round-8 proven shape): one node per wave, dword gather,
// 8-neighbor groups (4 loads in flight per lane). Writes packed bf16 h1.
__global__ void k_agg2(const ushort_t* __restrict__ hb, ushort_t* __restrict__ h1b,
                       const int* __restrict__ rowstart, const int* __restrict__ rowlen,
                       const int* __restrict__ cols, const float* __restrict__ dinv) {
  int node = blockIdx.x * 4 + (threadIdx.x >> 6);
  int lane = threadIdx.x & 63;
  if (node >= N_NODES) return;
  int half = lane >> 5;
  int fl = lane & 31;
  const unsigned* hb32 = (const unsigned*)hb;      // hb32[s*32+fl] = feats {2fl, 2fl+1}
  unsigned* o32 = (unsigned*)h1b;
  float2 acc;
  if (half == 0) {                                  // self loop (bf16)
    unsigned u = hb32[node * 32 + fl];
    acc.x = bfu_lo(u); acc.y = bfu_hi(u);
  } else { acc.x = 0.f; acc.y = 0.f; }
  int base = rowstart[node];
  int len = rowlen[node];
  for (int c0 = 0; c0 < len; c0 += 64) {
    int rem = len - c0;
    int m = rem < 64 ? rem : 64;
    int cidx = (lane < m) ? cols[base + c0 + lane] : 0;
    int j = 0;
    for (; j + 8 <= m; j += 8) {   // 8 neighbors / iter, 4 dword loads in flight per lane
      int sA = __shfl(cidx, j + half);
      int sB = __shfl(cidx, j + 2 + half);
      int sC = __shfl(cidx, j + 4 + half);
      int sD = __shfl(cidx, j + 6 + half);
      unsigned uA = hb32[sA * 32 + fl], uB = hb32[sB * 32 + fl];
      unsigned uC = hb32[sC * 32 + fl], uD = hb32[sD * 32 + fl];
      acc.x += (bfu_lo(uA) + bfu_lo(uB)) + (bfu_lo(uC) + bfu_lo(uD));
      acc.y += (bfu_hi(uA) + bfu_hi(uB)) + (bfu_hi(uC) + bfu_hi(uD));
    }
    for (; j + 2 <= m; j += 2) {
      int s = __shfl(cidx, j + half);
      unsigned u = hb32[s * 32 + fl];
      acc.x += bfu_lo(u);
      acc.y += bfu_hi(u);
    }
    if (j < m) {                   // odd leftover: half0 only
      int s = __shfl(cidx, j);
      if (half == 0) {
        unsigned u = hb32[s * 32 + fl];
        acc.x += bfu_lo(u);
        acc.y += bfu_hi(u);
      }
    }
  }
  acc.x += __shfl_xor(acc.x, 32);
  acc.y += __shfl_xor(acc.y, 32);
  if (half == 0) {
    float dv = dinv[node];
    float ox = acc.x * dv, oy = acc.y * dv;
    o32[node * 32 + fl] = ((unsigned)f32_to_bf16(oy) << 16) | (unsigned)f32_to_bf16(ox);
  }
}

// BN2 stats from packed bf16 h1 -> stats[0:64], stats[64:128]
__global__ void k_bnstats_b(const ushort_t* __restrict__ h1b, float* __restrict__ stats) {
  const unsigned* h32 = (const unsigned*)h1b;
  int tid = threadIdx.x;
  int lane = tid & 63, wid = tid >> 6;
  int fl = lane & 31, rsel = lane >> 5;
  float s0 = 0.f, s1 = 0.f, q0 = 0.f, q1 = 0.f;
  for (int r = blockIdx.x * 8 + wid * 2 + rsel; r < N_NODES; r += gridDim.x * 8) {
    unsigned u = h32[r * 32 + fl];
    float a = bfu_lo(u), b = bfu_hi(u);
    s0 += a; s1 += b; q0 += a * a; q1 += b * b;
  }
  s0 += __shfl_xor(s0, 32); s1 += __shfl_xor(s1, 32);
  q0 += __shfl_xor(q0, 32); q1 += __shfl_xor(q1, 32);
  __shared__ float ls[4][64], lq[4][64];
  if (rsel == 0) {
    ls[wid][2 * fl] = s0; ls[wid][2 * fl + 1] = s1;
    lq[wid][2 * fl] = q0; lq[wid][2 * fl + 1] = q1;
  }
  __syncthreads();
  if (tid < 64) {
    float a = ls[0][tid] + ls[1][tid] + ls[2][tid] + ls[3][tid];
    float b = lq[0][tid] + lq[1][tid] + lq[2][tid] + lq[3][tid];
    atomicAdd(&stats[tid], a);
    atomicAdd(&stats[64 + tid], b);
  }
}

// ---------------- fused pooling + head (one block per graph; no grid sync needed) ----------------

__global__ void __launch_bounds__(256) k_poolhead(const ushort_t* __restrict__ h1b,
                                                  const float* __restrict__ stats2,
                                                  const float* __restrict__ gamma,
                                                  const float* __restrict__ beta,
                                                  const int* __restrict__ batch,
                                                  const int* __restrict__ recipe,
                                                  const float* __restrict__ emb,
                                                  const float* __restrict__ conv_w,
                                                  const float* __restrict__ conv_b,
                                                  const float* __restrict__ fc_w,
                                                  const float* __restrict__ fc_b,
                                                  const float* __restrict__ m1_w,
                                                  const float* __restrict__ m1_b,
                                                  const float* __restrict__ m2_w,
                                                  const float* __restrict__ m2_b,
                                                  const float* __restrict__ m3_w,
                                                  const float* __restrict__ m3_b,
                                                  float* __restrict__ out) {
  __shared__ float ssum[4][64], smax[4][64];
  __shared__ float cvec[192];
  __shared__ int sb[2];
  int g = blockIdx.x;
  int tid = threadIdx.x;
  int lane = tid & 63, wid = tid >> 6;

  // -------- pool phase --------
  if (tid < 2) {
    int tg = g + tid;
    int lo = 0, hi = N_NODES;
    while (lo < hi) {
      int mid = (lo + hi) >> 1;
      if (batch[mid] < tg) lo = mid + 1; else hi = mid;
    }
    sb[tid] = lo;
  }
  __syncthreads();
  int s0g = sb[0], s1g = sb[1];
  {
    float mu = stats2[lane] * (1.0f / N_NODES);
    float var = stats2[64 + lane] * (1.0f / N_NODES) - mu * mu;
    float sc = rsqrtf(var + EPS) * gamma[lane];
    float sh = beta[lane] - mu * sc;
    float sum = 0.f, mx = 0.f;
    for (int r = s0g + wid; r < s1g; r += 4) {
      float v = bf16_to_f32(h1b[r * 64 + lane]) * sc + sh;
      v = v > 0.f ? v : 0.f;
      sum += v;
      mx = v > mx ? v : mx;
    }
    ssum[wid][lane] = sum;
    smax[wid][lane] = mx;
  }
  __syncthreads();
  if (wid == 0) {
    float s = ssum[0][lane] + ssum[1][lane] + ssum[2][lane] + ssum[3][lane];
    float m = fmaxf(fmaxf(smax[0][lane], smax[1][lane]), fmaxf(smax[2][lane], smax[3][lane]));
    int cnt = s1g - s0g;
    float inv = 1.0f / (float)(cnt > 0 ? cnt : 1);
    cvec[lane] = s * inv;
    cvec[64 + lane] = m;
  }
  __syncthreads();

  // -------- head phase --------
  __shared__ float r_s[RLEN][EMBED];
  __shared__ float convout[16 * RLEN];
  __shared__ float y1[128];
  __shared__ float y2[64];
  __shared__ int rec_s[RLEN];
  __shared__ float emb_s[80];
  if (tid < 80) emb_s[tid] = emb[tid];
  if (tid < RLEN) rec_s[tid] = recipe[g * RLEN + tid];
  __syncthreads();
  for (int idx = tid; idx < RLEN * EMBED; idx += blockDim.x) {
    int pos = idx >> 3, e = idx & 7;
    r_s[pos][e] = emb_s[rec_s[pos] * EMBED + e];
  }
  __syncthreads();
  for (int idx = tid; idx < 16 * RLEN; idx += blockDim.x) {
    int c = idx / RLEN, pos = idx % RLEN;
    float acc = conv_b[c];
    #pragma unroll
    for (int k = 0; k < 3; ++k) {
      int p = pos + k - 1;
      if (p >= 0 && p < RLEN) {
        #pragma unroll
        for (int e = 0; e < EMBED; ++e)
          acc = fmaf(r_s[p][e], conv_w[(c * EMBED + e) * 3 + k], acc);
      }
    }
    convout[c * RLEN + pos] = acc > 0.f ? acc : 0.f;  // channel-major flatten
  }
  __syncthreads();
  if (tid < 64) {
    float acc = fc_b[tid];
    for (int i = 0; i < 320; ++i) acc = fmaf(convout[i], fc_w[i * 64 + tid], acc);
    cvec[128 + tid] = acc > 0.f ? acc : 0.f;
  }
  __syncthreads();
  if (tid < 128) {
    float acc = m1_b[tid];
    for (int i = 0; i < 192; ++i) acc = fmaf(cvec[i], m1_w[i * 128 + tid], acc);
    y1[tid] = acc > 0.f ? acc : 0.f;
  }
  __syncthreads();
  if (tid < 64) {
    float acc = m2_b[tid];
    for (int i = 0; i < 128; ++i) acc = fmaf(y1[i], m2_w[i * 64 + tid], acc);
    y2[tid] = acc > 0.f ? acc : 0.f;
  }
  __syncthreads();
  if (tid < 3) {
    float acc = m3_b[tid];
    for (int i = 0; i < 64; ++i) acc = fmaf(y2[i], m3_w[i * 3 + tid], acc);
    out[g * 3 + tid] = acc;
  }
}

extern "C" void kernel_launch(void* const* d_in, const int* in_sizes, int n_in,
                              void* d_out, int out_size, void* d_ws, size_t ws_size,
                              hipStream_t stream) {
  const float* x      = (const float*)d_in[0];
  const float* W1     = (const float*)d_in[1];
  // b1 (d_in[2]) cancels under BN
  const float* gamma1 = (const float*)d_in[3];
  const float* beta1  = (const float*)d_in[4];
  const float* W2     = (const float*)d_in[5];
  // b2 (d_in[6]) cancels under BN
  const float* gamma2 = (const float*)d_in[7];
  const float* beta2  = (const float*)d_in[8];
  const float* emb    = (const float*)d_in[9];
  const float* conv_w = (const float*)d_in[10];
  const float* conv_b = (const float*)d_in[11];
  const float* fc_w   = (const float*)d_in[12];
  const float* fc_b   = (const float*)d_in[13];
  const float* m1_w   = (const float*)d_in[14];
  const float* m1_b   = (const float*)d_in[15];
  const float* m2_w   = (const float*)d_in[16];
  const float* m2_b   = (const float*)d_in[17];
  const float* m3_w   = (const float*)d_in[18];
  const float* m3_b   = (const float*)d_in[19];
  const int* ei       = (const int*)d_in[20];
  const int* batch    = (const int*)d_in[21];
  const int* recipe   = (const int*)d_in[22];
  const int* e_src = ei;
  const int* e_dst = ei + N_EDGES;
  float* out = (float*)d_out;

  char* p = (char*)d_ws;
  auto alloc = [&](size_t bytes) {
    char* r = p;
    p += (bytes + 255) & ~(size_t)255;
    return (void*)r;
  };
  // zero-init group first (contiguous): one memset covers all three
  int*   bcursor  = (int*)alloc((size_t)NBKT * 4);     // 1024 B padded
  float* stats    = (float*)alloc(256 * 4);            // 1024 B
  float* mom      = (float*)alloc(16 * 4);             // 256 B
  float* dinv     = (float*)alloc((size_t)N_NODES * 4);
  int*   rowstart = (int*)alloc((size_t)N_NODES * 4);
  int*   rowlen   = (int*)alloc((size_t)N_NODES * 4);
  int*   cols     = (int*)alloc((size_t)NBKT * CAP * 4);
  float4* xs      = (float4*)alloc((size_t)N_NODES * 16);
  float4* tbuf    = (float4*)alloc((size_t)N_NODES * 16);
  int*   ebuf     = (int*)alloc((size_t)NBKT * CAP * 4);
  ushort_t* hb    = (ushort_t*)alloc((size_t)N_NODES * 64 * 2);
  ushort_t* h1b   = (ushort_t*)ebuf;  // alias: ebuf dead before k_agg2 writes h1b

  hipMemsetAsync(bcursor, 0, 2304, stream);  // bcursor(1024) + stats(1024) + mom(256)

  k_bscatter<<<(N_EDGES + CHUNK - 1) / CHUNK, 512, 0, stream>>>(e_src, e_dst, bcursor, ebuf);
  k_bfill<<<NBKT, 1024, 0, stream>>>(bcursor, ebuf, x, rowstart, rowlen, dinv, xs, cols);
  k_agg1<<<(N_NODES + 255) / 256, 256, 0, stream>>>(xs, tbuf, rowstart, rowlen, cols, dinv, mom);
  k_l2m2<<<625, 256, 0, stream>>>(tbuf, hb, W1, W2, mom, gamma1, beta1, dinv);
  k_agg2<<<(N_NODES + 3) / 4, 256, 0, stream>>>(hb, h1b, rowstart, rowlen, cols, dinv);
  k_bnstats_b<<<512, 256, 0, stream>>>(h1b, stats);
  k_poolhead<<<N_GRAPHS, 256, 0, stream>>>(h1b, stats, gamma2, beta2, batch, recipe, emb,
                                           conv_w, conv_b, fc_w, fc_b,
                                           m1_w, m1_b, m2_w, m2_b, m3_w, m3_b, out);
}